// Round 1
// baseline (16912.741 us; speedup 1.0000x reference)
//
#include <hip/hip_runtime.h>
#include <float.h>
#include <math.h>

#define EPSF 1e-5f
#define EPSD 1e-5

constexpr int B_  = 8;
constexpr int CIN = 512;
constexpr int T_  = 4096;
constexpr int K_  = 8;
constexpr int N_  = 2048;
constexpr int D_  = 256;
constexpr int BT  = B_ * T_;          // 32768 tokens
constexpr float MARGIN = 0.5f;        // fp32-scan uncertainty << 0.5

// ---------------------------------------------------------------------------
// prep: inv[k][n] = 1/clamp(usage), nrm[k][n] = sum_d (s/clamp(u))^2   (fp32)
// one wave per (k,n) row
// ---------------------------------------------------------------------------
__global__ void __launch_bounds__(256) prep_kernel(const float* __restrict__ embed_sum,
                                                   const float* __restrict__ usage,
                                                   float* __restrict__ inv,
                                                   float* __restrict__ nrm) {
  int w    = threadIdx.x >> 6;   // wave 0..3
  int lane = threadIdx.x & 63;
  int kn   = blockIdx.x * 4 + w;
  const float* s = embed_sum + (size_t)kn * D_;
  float um = fmaxf(usage[kn], EPSF);
  float4 sv = *(const float4*)(s + lane * 4);
  float e0 = sv.x / um, e1 = sv.y / um, e2 = sv.z / um, e3 = sv.w / um;
  float v = e0 * e0 + e1 * e1 + e2 * e2 + e3 * e3;
  for (int off = 32; off > 0; off >>= 1) v += __shfl_down(v, off);
  if (lane == 0) { inv[kn] = 1.0f / um; nrm[kn] = v; }
}

// ---------------------------------------------------------------------------
// input projection -> residual init.  x[bt][d] = sum_c w_in[d][c]*emb[b][c][t]
// block: 64 tokens, 256 threads = 4 d-groups x 64 t.  Weights via s_load
// (wave-uniform index through readfirstlane), activations coalesced to regs.
// ---------------------------------------------------------------------------
__global__ void __launch_bounds__(256) proj_r_kernel(const float* __restrict__ emb,
                                                     const float* __restrict__ w_in,
                                                     float* __restrict__ r) {
  int blk = blockIdx.x;
  int b   = blk >> 6;
  int t0  = (blk & 63) * 64;
  int tt  = threadIdx.x & 63;
  int dg  = threadIdx.x >> 6;
  int dgu = __builtin_amdgcn_readfirstlane(dg);

  float acc[64];
#pragma unroll
  for (int i = 0; i < 64; i++) acc[i] = 0.f;

  for (int c0 = 0; c0 < CIN; c0 += 32) {
    float rv[32];
#pragma unroll
    for (int cc = 0; cc < 32; cc++)
      rv[cc] = emb[((size_t)b * CIN + (c0 + cc)) * T_ + t0 + tt];
#pragma unroll
    for (int i = 0; i < 64; i++) {
      const float* wrow = w_in + (size_t)(dgu * 64 + i) * CIN + c0;
#pragma unroll
      for (int cc = 0; cc < 32; cc++)
        acc[i] += wrow[cc] * rv[cc];
    }
  }
  float* rp = r + ((size_t)(b * T_ + t0 + tt)) * D_ + dgu * 64;
#pragma unroll
  for (int i = 0; i < 64; i += 4) {
    float4 v = make_float4(acc[i], acc[i + 1], acc[i + 2], acc[i + 3]);
    *(float4*)(rp + i) = v;
  }
}

// ---------------------------------------------------------------------------
// One RVQ step.  Block: 32 tokens, 256 threads = 8 n-lanes x 32 tokens.
// r tile staged in LDS as [d4][token] float4.  Each thread scans n = j mod 8,
// 8 entries at a time, tracking top-2.  Near-ties (<MARGIN) rescored in fp64
// mirroring the reference formula.  Then residual update + code write.
// ---------------------------------------------------------------------------
__global__ void __launch_bounds__(256) rvq_step_kernel(const float* __restrict__ embed_sum,
                                                       const float* __restrict__ usage,
                                                       const float* __restrict__ inv,
                                                       const float* __restrict__ nrm,
                                                       float* __restrict__ r,
                                                       float* __restrict__ codes_f,
                                                       int k) {
  __shared__ float4 rs4[64][32];      // 32 KB  r tile, [d/4][token]
  __shared__ float  cs[32][8][2];     // per-thread top-2 scores
  __shared__ int    cn[32][8][2];     // per-thread top-2 indices
  __shared__ int    widx[32];

  int tid = threadIdx.x;
  int j   = tid >> 5;                 // 0..7  n-lane
  int tt  = tid & 31;                 // token in tile
  int bt0 = blockIdx.x * 32;

  const float* es_k  = embed_sum + (size_t)k * N_ * D_;
  const float* us_k  = usage     + (size_t)k * N_;
  const float* inv_k = inv       + (size_t)k * N_;
  const float* nrm_k = nrm       + (size_t)k * N_;

  // stage r tile
  for (int p = 0; p < 8; p++) {
    int flat = tid + p * 256;         // 0..2047
    int d4 = flat >> 5, ttl = flat & 31;
    rs4[d4][ttl] = *(const float4*)(r + (size_t)(bt0 + ttl) * D_ + d4 * 4);
  }
  __syncthreads();

  float b1s = FLT_MAX, b2s = FLT_MAX;
  int   b1n = 0,       b2n = 0;

  for (int nb = 0; nb < N_; nb += 64) {
    float acc[8];
#pragma unroll
    for (int m = 0; m < 8; m++) acc[m] = 0.f;
    const float* ep = es_k + (size_t)(nb + j) * D_;
    for (int d4 = 0; d4 < 64; d4++) {
      float4 rv = rs4[d4][tt];
#pragma unroll
      for (int m = 0; m < 8; m++) {
        float4 ev = *(const float4*)(ep + m * 8 * D_ + d4 * 4);
        acc[m] += rv.x * ev.x + rv.y * ev.y + rv.z * ev.z + rv.w * ev.w;
      }
    }
#pragma unroll
    for (int m = 0; m < 8; m++) {
      int n = nb + j + 8 * m;
      float s = nrm_k[n] - 2.0f * inv_k[n] * acc[m];
      if (s < b1s)      { b2s = b1s; b2n = b1n; b1s = s; b1n = n; }
      else if (s < b2s) { b2s = s; b2n = n; }
    }
  }
  cs[tt][j][0] = b1s; cs[tt][j][1] = b2s;
  cn[tt][j][0] = b1n; cn[tt][j][1] = b2n;
  __syncthreads();

  if (tid < 32) {
    int t = tid;
    float g1s = FLT_MAX, g2s = FLT_MAX;
    int   g1n = 0,       g2n = 0;
    for (int jj = 0; jj < 8; jj++) {
      for (int q = 0; q < 2; q++) {
        float s = cs[t][jj][q];
        int   n = cn[t][jj][q];
        if (s < g1s || (s == g1s && n < g1n)) { g2s = g1s; g2n = g1n; g1s = s; g1n = n; }
        else if (s < g2s || (s == g2s && n < g2n)) { g2s = s; g2n = n; }
      }
    }
    int winner = g1n;
    if (g2s - g1s < MARGIN && g2n != g1n) {
      // fp64 rescore of both candidates (matches np float64 reference math)
      double sc[2];
      int nn[2] = { g1n, g2n };
      for (int c = 0; c < 2; c++) {
        double u    = fmax((double)us_k[nn[c]], EPSD);
        double uinv = 1.0 / u;
        const float* srow = es_k + (size_t)nn[c] * D_;
        double dotre = 0.0, ee = 0.0;
        for (int d = 0; d < D_; d++) {
          double e   = (double)srow[d] * uinv;
          double rvd = (double)((const float*)&rs4[d >> 2][t])[d & 3];
          dotre += rvd * e;
          ee    += e * e;
        }
        sc[c] = ee - 2.0 * dotre;
      }
      if (sc[1] < sc[0] || (sc[1] == sc[0] && nn[1] < nn[0])) winner = nn[1];
    }
    widx[t] = winner;
    codes_f[(size_t)k * BT + bt0 + t] = (float)winner;
  }
  __syncthreads();

  // residual update: r -= embed[idx]  (f32 division matches reference embeds)
  {
    int n = widx[tt];
    float um = fmaxf(us_k[n], EPSF);
    const float* srow = es_k + (size_t)n * D_;
    float* rp = r + (size_t)(bt0 + tt) * D_;
    for (int p = 0; p < 8; p++) {
      int d4 = j + 8 * p;
      float4 rv = rs4[d4][tt];
      float4 sv = *(const float4*)(srow + d4 * 4);
      rv.x -= sv.x / um; rv.y -= sv.y / um; rv.z -= sv.z / um; rv.w -= sv.w / um;
      *(float4*)(rp + d4 * 4) = rv;
    }
  }
}

// ---------------------------------------------------------------------------
// output projection: recompute x tile (bitwise-identical to proj_r), read
// final residual, q = x - r, out[b][c][t] = sum_d w_out[c][d] * q
// ---------------------------------------------------------------------------
__global__ void __launch_bounds__(256) out_proj_kernel(const float* __restrict__ emb,
                                                       const float* __restrict__ w_in,
                                                       const float* __restrict__ w_out,
                                                       const float* __restrict__ r,
                                                       float* __restrict__ out) {
  __shared__ float xl[256][64];       // 64 KB x tile, [d][token]
  int blk = blockIdx.x;
  int b   = blk >> 6;
  int t0  = (blk & 63) * 64;
  int tt  = threadIdx.x & 63;
  int dg  = threadIdx.x >> 6;
  int dgu = __builtin_amdgcn_readfirstlane(dg);

  // phase A: recompute x tile
  {
    float acc[64];
#pragma unroll
    for (int i = 0; i < 64; i++) acc[i] = 0.f;
    for (int c0 = 0; c0 < CIN; c0 += 32) {
      float rv[32];
#pragma unroll
      for (int cc = 0; cc < 32; cc++)
        rv[cc] = emb[((size_t)b * CIN + (c0 + cc)) * T_ + t0 + tt];
#pragma unroll
      for (int i = 0; i < 64; i++) {
        const float* wrow = w_in + (size_t)(dgu * 64 + i) * CIN + c0;
#pragma unroll
        for (int cc = 0; cc < 32; cc++)
          acc[i] += wrow[cc] * rv[cc];
      }
    }
#pragma unroll
    for (int i = 0; i < 64; i++) xl[dgu * 64 + i][tt] = acc[i];
  }
  __syncthreads();

  // phase B: project q = x - r with w_out (two c-halves of 256)
  const float* rp = r + (size_t)(b * T_ + t0 + tt) * D_;
  for (int half = 0; half < 2; half++) {
    float acc[64];
#pragma unroll
    for (int i = 0; i < 64; i++) acc[i] = 0.f;
    for (int d0 = 0; d0 < D_; d0 += 4) {
      float4 rq = *(const float4*)(rp + d0);
      float q0 = xl[d0 + 0][tt] - rq.x;
      float q1 = xl[d0 + 1][tt] - rq.y;
      float q2 = xl[d0 + 2][tt] - rq.z;
      float q3 = xl[d0 + 3][tt] - rq.w;
#pragma unroll
      for (int i = 0; i < 64; i++) {
        const float* wrow = w_out + (size_t)(half * 256 + dgu * 64 + i) * D_ + d0;
        acc[i] += wrow[0] * q0 + wrow[1] * q1 + wrow[2] * q2 + wrow[3] * q3;
      }
    }
    float* op = out + (size_t)b * CIN * T_ + (size_t)(half * 256 + dgu * 64) * T_ + t0 + tt;
#pragma unroll
    for (int i = 0; i < 64; i++) op[(size_t)i * T_] = acc[i];
  }
}

// ---------------------------------------------------------------------------
extern "C" void kernel_launch(void* const* d_in, const int* in_sizes, int n_in,
                              void* d_out, int out_size, void* d_ws, size_t ws_size,
                              hipStream_t stream) {
  const float* emb       = (const float*)d_in[0];  // [B, Cin, T]
  const float* w_in      = (const float*)d_in[1];  // [D, Cin]
  const float* w_out     = (const float*)d_in[2];  // [Cin, D]
  const float* embed_sum = (const float*)d_in[3];  // [K, N, D]
  const float* usage     = (const float*)d_in[4];  // [K, N]

  float* outp    = (float*)d_out;
  float* codes_f = outp;                 // K*B*T floats (codes as float values)
  float* proj_o  = outp + (size_t)K_ * BT;

  float* ws  = (float*)d_ws;
  float* rb  = ws;                       // residual, BT*D floats (33.6 MB)
  float* inv = ws + (size_t)BT * D_;     // K*N
  float* nrm = inv + (size_t)K_ * N_;    // K*N

  hipLaunchKernelGGL(prep_kernel, dim3(K_ * N_ / 4), dim3(256), 0, stream,
                     embed_sum, usage, inv, nrm);
  hipLaunchKernelGGL(proj_r_kernel, dim3(B_ * T_ / 64), dim3(256), 0, stream,
                     emb, w_in, rb);
  for (int k = 0; k < K_; k++)
    hipLaunchKernelGGL(rvq_step_kernel, dim3(BT / 32), dim3(256), 0, stream,
                       embed_sum, usage, inv, nrm, rb, codes_f, k);
  hipLaunchKernelGGL(out_proj_kernel, dim3(B_ * T_ / 64), dim3(256), 0, stream,
                     emb, w_in, w_out, rb, proj_o);
}

// Round 2
// 2850.248 us; speedup vs baseline: 5.9338x; 5.9338x over previous
//
#include <hip/hip_runtime.h>
#include <float.h>
#include <math.h>

#define EPSF 1e-5f

constexpr int B_  = 8;
constexpr int CIN = 512;
constexpr int T_  = 4096;
constexpr int K_  = 8;
constexpr int N_  = 2048;
constexpr int D_  = 256;
constexpr int BT  = B_ * T_;          // 32768 tokens

typedef _Float16 v8h __attribute__((ext_vector_type(8)));
typedef _Float16 v4h __attribute__((ext_vector_type(4)));
typedef float    v4f __attribute__((ext_vector_type(4)));

// ---------------------------------------------------------------------------
// prep: inv = 1/clamp(u), nrm = sum_d e^2 (fp32, e = s/clamp(u)); also writes
// the f16 codebook in MFMA-B-fragment-swizzled order:
//   ehs[k][half][chunk][cg 0..31][r 0..15] x 16B  (chunk=16 codes, cg=8 dims)
// so scan staging is a fully linear 16B/thread copy.
// ---------------------------------------------------------------------------
__global__ void __launch_bounds__(256) prep_kernel(const float* __restrict__ embed_sum,
                                                   const float* __restrict__ usage,
                                                   float* __restrict__ inv,
                                                   float* __restrict__ nrm,
                                                   _Float16* __restrict__ ehs) {
  int w    = threadIdx.x >> 6;
  int lane = threadIdx.x & 63;
  int kn   = blockIdx.x * 4 + w;
  int k    = kn >> 11, n = kn & (N_ - 1);
  const float* s = embed_sum + (size_t)kn * D_;
  float um = fmaxf(usage[kn], EPSF);
  float4 sv = *(const float4*)(s + lane * 4);
  float e0 = sv.x / um, e1 = sv.y / um, e2 = sv.z / um, e3 = sv.w / um;
  float v = e0 * e0 + e1 * e1 + e2 * e2 + e3 * e3;

  int half = n >> 10, chunk = (n >> 4) & 63, r = n & 15;
  int cg = lane >> 1, sub = lane & 1;
  v4h h4; h4[0] = (_Float16)e0; h4[1] = (_Float16)e1;
  h4[2] = (_Float16)e2; h4[3] = (_Float16)e3;
  size_t off16 = ((size_t)((k * 2 + half) * 64 + chunk)) * 4096
               + (size_t)(cg * 16 + r) * 8 + (size_t)sub * 4;   // f16 units
  *(v4h*)(ehs + off16) = h4;

  for (int off = 32; off > 0; off >>= 1) v += __shfl_down(v, off);
  if (lane == 0) { inv[kn] = 1.0f / um; nrm[kn] = v; }
}

// ---------------------------------------------------------------------------
// input projection -> residual init (unchanged from proven round-1 kernel)
// ---------------------------------------------------------------------------
__global__ void __launch_bounds__(256) proj_r_kernel(const float* __restrict__ emb,
                                                     const float* __restrict__ w_in,
                                                     float* __restrict__ r) {
  int blk = blockIdx.x;
  int b   = blk >> 6;
  int t0  = (blk & 63) * 64;
  int tt  = threadIdx.x & 63;
  int dg  = threadIdx.x >> 6;
  int dgu = __builtin_amdgcn_readfirstlane(dg);

  float acc[64];
#pragma unroll
  for (int i = 0; i < 64; i++) acc[i] = 0.f;

  for (int c0 = 0; c0 < CIN; c0 += 32) {
    float rv[32];
#pragma unroll
    for (int cc = 0; cc < 32; cc++)
      rv[cc] = emb[((size_t)b * CIN + (c0 + cc)) * T_ + t0 + tt];
#pragma unroll
    for (int i = 0; i < 64; i++) {
      const float* wrow = w_in + (size_t)(dgu * 64 + i) * CIN + c0;
#pragma unroll
      for (int cc = 0; cc < 32; cc++)
        acc[i] += wrow[cc] * rv[cc];
    }
  }
  float* rp = r + ((size_t)(b * T_ + t0 + tt)) * D_ + dgu * 64;
#pragma unroll
  for (int i = 0; i < 64; i += 4) {
    float4 v = make_float4(acc[i], acc[i + 1], acc[i + 2], acc[i + 3]);
    *(float4*)(rp + i) = v;
  }
}

// ---------------------------------------------------------------------------
// MFMA scan: per step, per (token-group 256, codebook-half 1024) block.
// 8 waves x 32 tokens (2 tiles of 16). A (f16 residual frags) in registers;
// B (swizzled f16 codebook) dbuf-staged in LDS, 1 barrier/chunk.
// Tracks top-3 (f16-score) per token; emits 3 candidate indices per half.
// ---------------------------------------------------------------------------
__global__ void __launch_bounds__(512) scan_kernel(const _Float16* __restrict__ ehs,
                                                   const float* __restrict__ nrm,
                                                   const float* __restrict__ rb,
                                                   int* __restrict__ cand, int k) {
  __shared__ v8h ldsB[2][512];          // 2 x 8 KB
  int tid  = threadIdx.x;
  int wave = tid >> 6, lane = tid & 63;
  int lr = lane & 15, lg = lane >> 4;
  int tg = blockIdx.x >> 1, half = blockIdx.x & 1;
  int wbase = tg * 256 + wave * 32;

  // A fragments: lane holds token (wbase + tau*16 + lr), k = c*32 + lg*8 + j
  v8h A[2][8];
#pragma unroll
  for (int tau = 0; tau < 2; tau++) {
    const float* rrow = rb + (size_t)(wbase + tau * 16 + lr) * D_;
#pragma unroll
    for (int c = 0; c < 8; c++) {
      int k0 = c * 32 + lg * 8;
      float4 f0 = *(const float4*)(rrow + k0);
      float4 f1 = *(const float4*)(rrow + k0 + 4);
      v8h a;
      a[0] = (_Float16)f0.x; a[1] = (_Float16)f0.y;
      a[2] = (_Float16)f0.z; a[3] = (_Float16)f0.w;
      a[4] = (_Float16)f1.x; a[5] = (_Float16)f1.y;
      a[6] = (_Float16)f1.z; a[7] = (_Float16)f1.w;
      A[tau][c] = a;
    }
  }

  const v8h* src = (const v8h*)(ehs + ((size_t)(k * 2 + half)) * (64 * 4096));
  ldsB[0][tid] = src[tid];              // stage chunk 0

  float b1s[8], b2s[8], b3s[8];
  int   b1n[8], b2n[8], b3n[8];
#pragma unroll
  for (int i = 0; i < 8; i++) {
    b1s[i] = b2s[i] = b3s[i] = FLT_MAX;
    b1n[i] = b2n[i] = b3n[i] = 0x7fffffff;
  }
  const float* nrm_k = nrm + (size_t)k * N_;
  __syncthreads();

  for (int ch = 0; ch < 64; ch++) {
    int cur = ch & 1;
    v8h nxt;
    bool more = (ch + 1 < 64);
    if (more) nxt = src[(size_t)(ch + 1) * 512 + tid];   // issue early (T14)

    v4f acc0 = {0.f, 0.f, 0.f, 0.f}, acc1 = {0.f, 0.f, 0.f, 0.f};
#pragma unroll
    for (int c = 0; c < 8; c++) {
      v8h Bf = ldsB[cur][(c * 4 + lg) * 16 + lr];
      acc0 = __builtin_amdgcn_mfma_f32_16x16x32_f16(A[0][c], Bf, acc0, 0, 0, 0);
      acc1 = __builtin_amdgcn_mfma_f32_16x16x32_f16(A[1][c], Bf, acc1, 0, 0, 0);
    }
    int n = half * 1024 + ch * 16 + lr;   // D col = lr
    float nv = nrm_k[n];
#pragma unroll
    for (int j = 0; j < 4; j++) {
      {
        float s = nv - 2.0f * acc0[j];
        bool c1 = s < b1s[j], c2 = s < b2s[j], c3 = s < b3s[j];
        float o2 = b2s[j]; int o2n = b2n[j];
        b3s[j] = c2 ? o2 : (c3 ? s : b3s[j]); b3n[j] = c2 ? o2n : (c3 ? n : b3n[j]);
        b2s[j] = c1 ? b1s[j] : (c2 ? s : o2); b2n[j] = c1 ? b1n[j] : (c2 ? n : o2n);
        b1s[j] = c1 ? s : b1s[j];             b1n[j] = c1 ? n : b1n[j];
      }
      {
        int i = 4 + j;
        float s = nv - 2.0f * acc1[j];
        bool c1 = s < b1s[i], c2 = s < b2s[i], c3 = s < b3s[i];
        float o2 = b2s[i]; int o2n = b2n[i];
        b3s[i] = c2 ? o2 : (c3 ? s : b3s[i]); b3n[i] = c2 ? o2n : (c3 ? n : b3n[i]);
        b2s[i] = c1 ? b1s[i] : (c2 ? s : o2); b2n[i] = c1 ? b1n[i] : (c2 ? n : o2n);
        b1s[i] = c1 ? s : b1s[i];             b1n[i] = c1 ? n : b1n[i];
      }
    }
    if (more) ldsB[cur ^ 1][tid] = nxt;   // write-late, other buffer
    __syncthreads();
  }

  // merge top-3 across the 16 lanes of each row-group (3x extract-min)
#pragma unroll
  for (int rI = 0; rI < 8; rI++) {
    float h1 = b1s[rI], h2 = b2s[rI], h3 = b3s[rI];
    int   m1 = b1n[rI], m2 = b2n[rI], m3 = b3n[rI];
    int o0 = 0, o1 = 0, o2v = 0;
#pragma unroll
    for (int round = 0; round < 3; round++) {
      float mb = h1; int mn = m1;
#pragma unroll
      for (int st = 1; st < 16; st <<= 1) {
        float ob = __shfl_xor(mb, st);
        int   on = __shfl_xor(mn, st);
        bool t = (ob < mb) || (ob == mb && on < mn);
        mb = t ? ob : mb; mn = t ? on : mn;
      }
      if (round == 0) o0 = mn; else if (round == 1) o1 = mn; else o2v = mn;
      bool own = (m1 == mn);
      h1 = own ? h2 : h1; m1 = own ? m2 : m1;
      h2 = own ? h3 : h2; m2 = own ? m3 : m2;
      h3 = own ? FLT_MAX : h3; m3 = own ? 0x7fffffff : m3;
    }
    if (lr == 0) {
      int token = wbase + (rI >= 4 ? 16 : 0) + lg * 4 + (rI & 3);  // D row = lg*4+j
      int* cp = cand + (size_t)token * 6 + half * 3;
      cp[0] = o0; cp[1] = o1; cp[2] = o2v;
    }
  }
}

// ---------------------------------------------------------------------------
// select: fp32-rescore the 6 candidates per token (round-1 formula), fp64
// escalate when gap < 0.5, write code, apply residual update (s/um math).
// 16 lanes per token, all selection done redundantly on the 16 lanes.
// ---------------------------------------------------------------------------
__global__ void __launch_bounds__(256) select_kernel(const float* __restrict__ embed_sum,
                                                     const float* __restrict__ usage,
                                                     const float* __restrict__ inv_,
                                                     const float* __restrict__ nrm,
                                                     const int* __restrict__ cand,
                                                     float* __restrict__ r,
                                                     float* __restrict__ codes_f, int k) {
  int tid = threadIdx.x;
  int sub = tid & 15, g = tid >> 4;
  int token = blockIdx.x * 16 + g;
  const float* es_k  = embed_sum + (size_t)k * N_ * D_;
  const float* us_k  = usage + (size_t)k * N_;
  const float* inv_k = inv_  + (size_t)k * N_;
  const float* nrm_k = nrm   + (size_t)k * N_;

  int c6[6];
#pragma unroll
  for (int i = 0; i < 6; i++) c6[i] = cand[(size_t)token * 6 + i];
  float* rrow = r + (size_t)token * D_;
  float4 rv[4];
#pragma unroll
  for (int q = 0; q < 4; q++) rv[q] = *(const float4*)(rrow + sub * 16 + q * 4);

  float dots[6];
#pragma unroll
  for (int i = 0; i < 6; i++) {
    const float* sr = es_k + (size_t)c6[i] * D_ + sub * 16;
    float a = 0.f;
#pragma unroll
    for (int q = 0; q < 4; q++) {
      float4 sv = *(const float4*)(sr + q * 4);
      a += rv[q].x * sv.x + rv[q].y * sv.y + rv[q].z * sv.z + rv[q].w * sv.w;
    }
    dots[i] = a;
  }
#pragma unroll
  for (int st = 1; st < 16; st <<= 1) {
#pragma unroll
    for (int i = 0; i < 6; i++) dots[i] += __shfl_xor(dots[i], st);
  }

  float bs = FLT_MAX, b2 = FLT_MAX; int bn = 0x7fffffff, bn2 = 0x7fffffff;
#pragma unroll
  for (int i = 0; i < 6; i++) {
    int n = c6[i];
    float s = nrm_k[n] - 2.0f * inv_k[n] * dots[i];
    bool better = (s < bs) || (s == bs && n < bn);
    bool second = (s < b2) || (s == b2 && n < bn2);
    if (better)      { b2 = bs; bn2 = bn; bs = s; bn = n; }
    else if (second) { b2 = s;  bn2 = n; }
  }
  int winner = bn;
  if (b2 - bs < 0.5f && bn2 != bn) {
    double sc[2]; int nn[2] = { bn, bn2 };
#pragma unroll
    for (int cI = 0; cI < 2; cI++) {
      double u = fmax((double)us_k[nn[cI]], 1e-5);
      double uinv = 1.0 / u;
      const float* srow = es_k + (size_t)nn[cI] * D_;
      double dotre = 0.0, ee = 0.0;
      for (int d = 0; d < D_; d++) {
        double e = (double)srow[d] * uinv;
        dotre += (double)rrow[d] * e;
        ee += e * e;
      }
      sc[cI] = ee - 2.0 * dotre;
    }
    if (sc[1] < sc[0] || (sc[1] == sc[0] && nn[1] < nn[0])) winner = nn[1];
  }

  float um = fmaxf(us_k[winner], EPSF);
  const float* sw = es_k + (size_t)winner * D_ + sub * 16;
#pragma unroll
  for (int q = 0; q < 4; q++) {
    float4 sv = *(const float4*)(sw + q * 4);
    rv[q].x -= sv.x / um; rv[q].y -= sv.y / um;
    rv[q].z -= sv.z / um; rv[q].w -= sv.w / um;
    *(float4*)(rrow + sub * 16 + q * 4) = rv[q];
  }
  if (sub == 0) codes_f[(size_t)k * BT + token] = (float)winner;
}

// ---------------------------------------------------------------------------
// output projection (unchanged from proven round-1 kernel)
// ---------------------------------------------------------------------------
__global__ void __launch_bounds__(256) out_proj_kernel(const float* __restrict__ emb,
                                                       const float* __restrict__ w_in,
                                                       const float* __restrict__ w_out,
                                                       const float* __restrict__ r,
                                                       float* __restrict__ out) {
  __shared__ float xl[256][64];
  int blk = blockIdx.x;
  int b   = blk >> 6;
  int t0  = (blk & 63) * 64;
  int tt  = threadIdx.x & 63;
  int dg  = threadIdx.x >> 6;
  int dgu = __builtin_amdgcn_readfirstlane(dg);

  {
    float acc[64];
#pragma unroll
    for (int i = 0; i < 64; i++) acc[i] = 0.f;
    for (int c0 = 0; c0 < CIN; c0 += 32) {
      float rv[32];
#pragma unroll
      for (int cc = 0; cc < 32; cc++)
        rv[cc] = emb[((size_t)b * CIN + (c0 + cc)) * T_ + t0 + tt];
#pragma unroll
      for (int i = 0; i < 64; i++) {
        const float* wrow = w_in + (size_t)(dgu * 64 + i) * CIN + c0;
#pragma unroll
        for (int cc = 0; cc < 32; cc++)
          acc[i] += wrow[cc] * rv[cc];
      }
    }
#pragma unroll
    for (int i = 0; i < 64; i++) xl[dgu * 64 + i][tt] = acc[i];
  }
  __syncthreads();

  const float* rp = r + (size_t)(b * T_ + t0 + tt) * D_;
  for (int half = 0; half < 2; half++) {
    float acc[64];
#pragma unroll
    for (int i = 0; i < 64; i++) acc[i] = 0.f;
    for (int d0 = 0; d0 < D_; d0 += 4) {
      float4 rq = *(const float4*)(rp + d0);
      float q0 = xl[d0 + 0][tt] - rq.x;
      float q1 = xl[d0 + 1][tt] - rq.y;
      float q2 = xl[d0 + 2][tt] - rq.z;
      float q3 = xl[d0 + 3][tt] - rq.w;
#pragma unroll
      for (int i = 0; i < 64; i++) {
        const float* wrow = w_out + (size_t)(half * 256 + dgu * 64 + i) * D_ + d0;
        acc[i] += wrow[0] * q0 + wrow[1] * q1 + wrow[2] * q2 + wrow[3] * q3;
      }
    }
    float* op = out + (size_t)b * CIN * T_ + (size_t)(half * 256 + dgu * 64) * T_ + t0 + tt;
#pragma unroll
    for (int i = 0; i < 64; i++) op[(size_t)i * T_] = acc[i];
  }
}

// ---------------------------------------------------------------------------
extern "C" void kernel_launch(void* const* d_in, const int* in_sizes, int n_in,
                              void* d_out, int out_size, void* d_ws, size_t ws_size,
                              hipStream_t stream) {
  const float* emb       = (const float*)d_in[0];
  const float* w_in      = (const float*)d_in[1];
  const float* w_out     = (const float*)d_in[2];
  const float* embed_sum = (const float*)d_in[3];
  const float* usage     = (const float*)d_in[4];

  float* outp    = (float*)d_out;
  float* codes_f = outp;
  float* proj_o  = outp + (size_t)K_ * BT;

  char*  ws   = (char*)d_ws;
  float* rb   = (float*)ws;                                  // 33.55 MB
  float* inv  = (float*)(ws + (size_t)BT * D_ * 4);
  float* nrm  = inv + (size_t)K_ * N_;
  int*   cand = (int*)(nrm + (size_t)K_ * N_);               // BT*6 ints
  _Float16* ehs = (_Float16*)((char*)(cand + (size_t)BT * 6));  // 8 MB f16

  hipLaunchKernelGGL(prep_kernel, dim3(K_ * N_ / 4), dim3(256), 0, stream,
                     embed_sum, usage, inv, nrm, ehs);
  hipLaunchKernelGGL(proj_r_kernel, dim3(B_ * T_ / 64), dim3(256), 0, stream,
                     emb, w_in, rb);
  for (int k = 0; k < K_; k++) {
    hipLaunchKernelGGL(scan_kernel, dim3(256), dim3(512), 0, stream,
                       ehs, nrm, rb, cand, k);
    hipLaunchKernelGGL(select_kernel, dim3(BT / 16), dim3(256), 0, stream,
                       embed_sum, usage, inv, nrm, cand, rb, codes_f, k);
  }
  hipLaunchKernelGGL(out_proj_kernel, dim3(B_ * T_ / 64), dim3(256), 0, stream,
                     emb, w_in, w_out, rb, proj_o);
}

// Round 3
// 1400.010 us; speedup vs baseline: 12.0804x; 2.0359x over previous
//
#include <hip/hip_runtime.h>
#include <float.h>
#include <math.h>

#define EPSF 1e-5f

constexpr int B_  = 8;
constexpr int CIN = 512;
constexpr int T_  = 4096;
constexpr int K_  = 8;
constexpr int N_  = 2048;
constexpr int D_  = 256;
constexpr int BT  = B_ * T_;          // 32768 tokens

typedef _Float16 v8h __attribute__((ext_vector_type(8)));
typedef _Float16 v4h __attribute__((ext_vector_type(4)));
typedef float    v4f __attribute__((ext_vector_type(4)));

// ---------------------------------------------------------------------------
// prep: inv = 1/clamp(u), nrm = sum_d e^2 (fp32); writes f16 codebook in
// MFMA-B-fragment-swizzled order (proven round-2 kernel, unchanged).
// ---------------------------------------------------------------------------
__global__ void __launch_bounds__(256) prep_kernel(const float* __restrict__ embed_sum,
                                                   const float* __restrict__ usage,
                                                   float* __restrict__ inv,
                                                   float* __restrict__ nrm,
                                                   _Float16* __restrict__ ehs) {
  int w    = threadIdx.x >> 6;
  int lane = threadIdx.x & 63;
  int kn   = blockIdx.x * 4 + w;
  int k    = kn >> 11, n = kn & (N_ - 1);
  const float* s = embed_sum + (size_t)kn * D_;
  float um = fmaxf(usage[kn], EPSF);
  float4 sv = *(const float4*)(s + lane * 4);
  float e0 = sv.x / um, e1 = sv.y / um, e2 = sv.z / um, e3 = sv.w / um;
  float v = e0 * e0 + e1 * e1 + e2 * e2 + e3 * e3;

  int half = n >> 10, chunk = (n >> 4) & 63, r = n & 15;
  int cg = lane >> 1, sub = lane & 1;
  v4h h4; h4[0] = (_Float16)e0; h4[1] = (_Float16)e1;
  h4[2] = (_Float16)e2; h4[3] = (_Float16)e3;
  size_t off16 = ((size_t)((k * 2 + half) * 64 + chunk)) * 4096
               + (size_t)(cg * 16 + r) * 8 + (size_t)sub * 4;
  *(v4h*)(ehs + off16) = h4;

  for (int off = 32; off > 0; off >>= 1) v += __shfl_down(v, off);
  if (lane == 0) { inv[kn] = 1.0f / um; nrm[kn] = v; }
}

// ---------------------------------------------------------------------------
// wprep_x: w_in [D][CIN] -> hi/lo f16 fragments.
// frag layout (verified by scan): lane&15 = row-or-col index (here d),
// (lane>>4)*8 = k-offset (here channel c), 8 consecutive k per lane.
// afragX[((mt*16 + kstep)*64 + lane)*2 + {0,1}]
// ---------------------------------------------------------------------------
__global__ void __launch_bounds__(64) wprep_x_kernel(const float* __restrict__ w_in,
                                                     v8h* __restrict__ afragX) {
  int lane = threadIdx.x;
  int mt = blockIdx.x >> 4, kstep = blockIdx.x & 15;
  int m = mt * 16 + (lane & 15), k0 = kstep * 32 + (lane >> 4) * 8;
  const float* src = w_in + (size_t)m * CIN + k0;
  float4 f0 = *(const float4*)src, f1 = *(const float4*)(src + 4);
  float e[8] = {f0.x, f0.y, f0.z, f0.w, f1.x, f1.y, f1.z, f1.w};
  v8h h, l;
#pragma unroll
  for (int j = 0; j < 8; j++) {
    _Float16 hh = (_Float16)e[j];
    h[j] = hh; l[j] = (_Float16)(e[j] - (float)hh);
  }
  v8h* dst = afragX + ((size_t)blockIdx.x * 64 + lane) * 2;
  dst[0] = h; dst[1] = l;
}

// ---------------------------------------------------------------------------
// wc: Wc[c][c'] = sum_d w_out[c][d] * w_in[d][c']   (fp32, 512x512)
// ---------------------------------------------------------------------------
__global__ void __launch_bounds__(256) wc_kernel(const float* __restrict__ w_out,
                                                 const float* __restrict__ w_in,
                                                 float* __restrict__ wc) {
  int c  = blockIdx.x >> 1;
  int cp = (blockIdx.x & 1) * 256 + threadIdx.x;
  float acc = 0.f;
  for (int d = 0; d < D_; d++)
    acc += w_out[(size_t)c * D_ + d] * w_in[(size_t)d * CIN + cp];
  wc[(size_t)c * CIN + cp] = acc;
}

// ---------------------------------------------------------------------------
// wprep_o: combined A matrix [512 c][768 k]: k<512 -> Wc, k>=512 -> -w_out.
// afragO[((mt*24 + kstep)*64 + lane)*2 + {0,1}]
// ---------------------------------------------------------------------------
__global__ void __launch_bounds__(64) wprep_o_kernel(const float* __restrict__ wc,
                                                     const float* __restrict__ w_out,
                                                     v8h* __restrict__ afragO) {
  int lane = threadIdx.x;
  int mt = blockIdx.x / 24, kstep = blockIdx.x % 24;
  int m = mt * 16 + (lane & 15), k0 = kstep * 32 + (lane >> 4) * 8;
  float e[8];
  if (k0 < CIN) {
    const float* s = wc + (size_t)m * CIN + k0;
#pragma unroll
    for (int j = 0; j < 8; j++) e[j] = s[j];
  } else {
    const float* s = w_out + (size_t)m * D_ + (k0 - CIN);
#pragma unroll
    for (int j = 0; j < 8; j++) e[j] = -s[j];
  }
  v8h h, l;
#pragma unroll
  for (int j = 0; j < 8; j++) {
    _Float16 hh = (_Float16)e[j];
    h[j] = hh; l[j] = (_Float16)(e[j] - (float)hh);
  }
  v8h* dst = afragO + ((size_t)blockIdx.x * 64 + lane) * 2;
  dst[0] = h; dst[1] = l;
}

// ---------------------------------------------------------------------------
// proj_x: x[token][d] = sum_c emb[b][c][t] * w_in[d][c]  via split-3 f16 MFMA.
// A = emb frags (m=token), B = w_in frags (n=d).  C: row=token, col=d ->
// coalesced float stores along d.
// ---------------------------------------------------------------------------
__global__ void __launch_bounds__(256, 2) proj_x_kernel(const float* __restrict__ emb,
                                                        const v8h* __restrict__ afragX,
                                                        float* __restrict__ rb) {
  int tid = threadIdx.x, wave = tid >> 6, lane = tid & 63;
  int lr = lane & 15, lg = lane >> 4;
  int t0 = blockIdx.x * 64 + wave * 16;
  int b  = t0 >> 12;
  const float* ebase = emb + (size_t)b * CIN * T_ + (t0 & (T_ - 1)) + lr;

  v4f acc[16];
#pragma unroll
  for (int nt = 0; nt < 16; nt++) acc[nt] = (v4f){0.f, 0.f, 0.f, 0.f};

  for (int ks = 0; ks < 16; ks++) {
    float e[8];
#pragma unroll
    for (int j = 0; j < 8; j++)
      e[j] = ebase[(size_t)(ks * 32 + lg * 8 + j) * T_];
    v8h Eh, El;
#pragma unroll
    for (int j = 0; j < 8; j++) {
      _Float16 hh = (_Float16)e[j];
      Eh[j] = hh; El[j] = (_Float16)(e[j] - (float)hh);
    }
    const v8h* ap = afragX + ((size_t)ks * 64 + lane) * 2;
#pragma unroll
    for (int nt = 0; nt < 16; nt++) {
      v8h Wh = ap[(size_t)nt * 2048];
      v8h Wl = ap[(size_t)nt * 2048 + 1];
      acc[nt] = __builtin_amdgcn_mfma_f32_16x16x32_f16(Eh, Wh, acc[nt], 0, 0, 0);
      acc[nt] = __builtin_amdgcn_mfma_f32_16x16x32_f16(El, Wh, acc[nt], 0, 0, 0);
      acc[nt] = __builtin_amdgcn_mfma_f32_16x16x32_f16(Eh, Wl, acc[nt], 0, 0, 0);
    }
  }
  // C: row = token = t0 + lg*4 + r, col = d = nt*16 + lr
#pragma unroll
  for (int nt = 0; nt < 16; nt++)
#pragma unroll
    for (int r = 0; r < 4; r++)
      rb[(size_t)(t0 + lg * 4 + r) * D_ + nt * 16 + lr] = acc[nt][r];
}

// ---------------------------------------------------------------------------
// proj_out: out[b][c][t] = sum_c' Wc[c][c']*emb[b][c'][t] - sum_d w_out[c][d]*r[t][d]
// One K=768 GEMM: A = [Wc | -w_out] frags (m=c), B = emb/r frags (n=token).
// C: row=c, col=token -> coalesced dword stores along t.
// ---------------------------------------------------------------------------
__global__ void __launch_bounds__(256, 2) proj_out_kernel(const float* __restrict__ emb,
                                                          const float* __restrict__ rb,
                                                          const v8h* __restrict__ afragO,
                                                          float* __restrict__ outb) {
  int tid = threadIdx.x, wave = tid >> 6, lane = tid & 63;
  int lr = lane & 15, lg = lane >> 4;
  int t0 = blockIdx.x * 64 + wave * 16;
  int b  = t0 >> 12;
  const float* ebase = emb + (size_t)b * CIN * T_ + (t0 & (T_ - 1)) + lr;

  v4f acc[32];
#pragma unroll
  for (int mt = 0; mt < 32; mt++) acc[mt] = (v4f){0.f, 0.f, 0.f, 0.f};

  for (int ks = 0; ks < 24; ks++) {
    float e[8];
    if (ks < 16) {
#pragma unroll
      for (int j = 0; j < 8; j++)
        e[j] = ebase[(size_t)(ks * 32 + lg * 8 + j) * T_];
    } else {
      const float* rrow = rb + (size_t)(t0 + lr) * D_ + (ks - 16) * 32 + lg * 8;
      float4 f0 = *(const float4*)rrow, f1 = *(const float4*)(rrow + 4);
      e[0] = f0.x; e[1] = f0.y; e[2] = f0.z; e[3] = f0.w;
      e[4] = f1.x; e[5] = f1.y; e[6] = f1.z; e[7] = f1.w;
    }
    v8h Bh, Bl;
#pragma unroll
    for (int j = 0; j < 8; j++) {
      _Float16 hh = (_Float16)e[j];
      Bh[j] = hh; Bl[j] = (_Float16)(e[j] - (float)hh);
    }
    const v8h* ap = afragO + ((size_t)ks * 64 + lane) * 2;
#pragma unroll
    for (int mt = 0; mt < 32; mt++) {
      v8h Ah = ap[(size_t)mt * 3072];
      v8h Al = ap[(size_t)mt * 3072 + 1];
      acc[mt] = __builtin_amdgcn_mfma_f32_16x16x32_f16(Ah, Bh, acc[mt], 0, 0, 0);
      acc[mt] = __builtin_amdgcn_mfma_f32_16x16x32_f16(Al, Bh, acc[mt], 0, 0, 0);
      acc[mt] = __builtin_amdgcn_mfma_f32_16x16x32_f16(Ah, Bl, acc[mt], 0, 0, 0);
    }
  }
  // C: row = c = mt*16 + lg*4 + r, col = token = t0 + lr
  float* op = outb + (size_t)b * CIN * T_ + (t0 & (T_ - 1)) + lr;
#pragma unroll
  for (int mt = 0; mt < 32; mt++)
#pragma unroll
    for (int r = 0; r < 4; r++)
      op[(size_t)(mt * 16 + lg * 4 + r) * T_] = acc[mt][r];
}

// ---------------------------------------------------------------------------
// MFMA scan (proven round-2 kernel, unchanged)
// ---------------------------------------------------------------------------
__global__ void __launch_bounds__(512) scan_kernel(const _Float16* __restrict__ ehs,
                                                   const float* __restrict__ nrm,
                                                   const float* __restrict__ rb,
                                                   int* __restrict__ cand, int k) {
  __shared__ v8h ldsB[2][512];
  int tid  = threadIdx.x;
  int wave = tid >> 6, lane = tid & 63;
  int lr = lane & 15, lg = lane >> 4;
  int tg = blockIdx.x >> 1, half = blockIdx.x & 1;
  int wbase = tg * 256 + wave * 32;

  v8h A[2][8];
#pragma unroll
  for (int tau = 0; tau < 2; tau++) {
    const float* rrow = rb + (size_t)(wbase + tau * 16 + lr) * D_;
#pragma unroll
    for (int c = 0; c < 8; c++) {
      int k0 = c * 32 + lg * 8;
      float4 f0 = *(const float4*)(rrow + k0);
      float4 f1 = *(const float4*)(rrow + k0 + 4);
      v8h a;
      a[0] = (_Float16)f0.x; a[1] = (_Float16)f0.y;
      a[2] = (_Float16)f0.z; a[3] = (_Float16)f0.w;
      a[4] = (_Float16)f1.x; a[5] = (_Float16)f1.y;
      a[6] = (_Float16)f1.z; a[7] = (_Float16)f1.w;
      A[tau][c] = a;
    }
  }

  const v8h* src = (const v8h*)(ehs + ((size_t)(k * 2 + half)) * (64 * 4096));
  ldsB[0][tid] = src[tid];

  float b1s[8], b2s[8], b3s[8];
  int   b1n[8], b2n[8], b3n[8];
#pragma unroll
  for (int i = 0; i < 8; i++) {
    b1s[i] = b2s[i] = b3s[i] = FLT_MAX;
    b1n[i] = b2n[i] = b3n[i] = 0x7fffffff;
  }
  const float* nrm_k = nrm + (size_t)k * N_;
  __syncthreads();

  for (int ch = 0; ch < 64; ch++) {
    int cur = ch & 1;
    v8h nxt;
    bool more = (ch + 1 < 64);
    if (more) nxt = src[(size_t)(ch + 1) * 512 + tid];

    v4f acc0 = {0.f, 0.f, 0.f, 0.f}, acc1 = {0.f, 0.f, 0.f, 0.f};
#pragma unroll
    for (int c = 0; c < 8; c++) {
      v8h Bf = ldsB[cur][(c * 4 + lg) * 16 + lr];
      acc0 = __builtin_amdgcn_mfma_f32_16x16x32_f16(A[0][c], Bf, acc0, 0, 0, 0);
      acc1 = __builtin_amdgcn_mfma_f32_16x16x32_f16(A[1][c], Bf, acc1, 0, 0, 0);
    }
    int n = half * 1024 + ch * 16 + lr;
    float nv = nrm_k[n];
#pragma unroll
    for (int j = 0; j < 4; j++) {
      {
        float s = nv - 2.0f * acc0[j];
        bool c1 = s < b1s[j], c2 = s < b2s[j], c3 = s < b3s[j];
        float o2 = b2s[j]; int o2n = b2n[j];
        b3s[j] = c2 ? o2 : (c3 ? s : b3s[j]); b3n[j] = c2 ? o2n : (c3 ? n : b3n[j]);
        b2s[j] = c1 ? b1s[j] : (c2 ? s : o2); b2n[j] = c1 ? b1n[j] : (c2 ? n : o2n);
        b1s[j] = c1 ? s : b1s[j];             b1n[j] = c1 ? n : b1n[j];
      }
      {
        int i = 4 + j;
        float s = nv - 2.0f * acc1[j];
        bool c1 = s < b1s[i], c2 = s < b2s[i], c3 = s < b3s[i];
        float o2 = b2s[i]; int o2n = b2n[i];
        b3s[i] = c2 ? o2 : (c3 ? s : b3s[i]); b3n[i] = c2 ? o2n : (c3 ? n : b3n[i]);
        b2s[i] = c1 ? b1s[i] : (c2 ? s : o2); b2n[i] = c1 ? b1n[i] : (c2 ? n : o2n);
        b1s[i] = c1 ? s : b1s[i];             b1n[i] = c1 ? n : b1n[i];
      }
    }
    if (more) ldsB[cur ^ 1][tid] = nxt;
    __syncthreads();
  }

#pragma unroll
  for (int rI = 0; rI < 8; rI++) {
    float h1 = b1s[rI], h2 = b2s[rI], h3 = b3s[rI];
    int   m1 = b1n[rI], m2 = b2n[rI], m3 = b3n[rI];
    int o0 = 0, o1 = 0, o2v = 0;
#pragma unroll
    for (int round = 0; round < 3; round++) {
      float mb = h1; int mn = m1;
#pragma unroll
      for (int st = 1; st < 16; st <<= 1) {
        float ob = __shfl_xor(mb, st);
        int   on = __shfl_xor(mn, st);
        bool t = (ob < mb) || (ob == mb && on < mn);
        mb = t ? ob : mb; mn = t ? on : mn;
      }
      if (round == 0) o0 = mn; else if (round == 1) o1 = mn; else o2v = mn;
      bool own = (m1 == mn);
      h1 = own ? h2 : h1; m1 = own ? m2 : m1;
      h2 = own ? h3 : h2; m2 = own ? m3 : m2;
      h3 = own ? FLT_MAX : h3; m3 = own ? 0x7fffffff : m3;
    }
    if (lr == 0) {
      int token = wbase + (rI >= 4 ? 16 : 0) + lg * 4 + (rI & 3);
      int* cp = cand + (size_t)token * 6 + half * 3;
      cp[0] = o0; cp[1] = o1; cp[2] = o2v;
    }
  }
}

// ---------------------------------------------------------------------------
// select (proven round-2 kernel, unchanged)
// ---------------------------------------------------------------------------
__global__ void __launch_bounds__(256) select_kernel(const float* __restrict__ embed_sum,
                                                     const float* __restrict__ usage,
                                                     const float* __restrict__ inv_,
                                                     const float* __restrict__ nrm,
                                                     const int* __restrict__ cand,
                                                     float* __restrict__ r,
                                                     float* __restrict__ codes_f, int k) {
  int tid = threadIdx.x;
  int sub = tid & 15, g = tid >> 4;
  int token = blockIdx.x * 16 + g;
  const float* es_k  = embed_sum + (size_t)k * N_ * D_;
  const float* us_k  = usage + (size_t)k * N_;
  const float* inv_k = inv_  + (size_t)k * N_;
  const float* nrm_k = nrm   + (size_t)k * N_;

  int c6[6];
#pragma unroll
  for (int i = 0; i < 6; i++) c6[i] = cand[(size_t)token * 6 + i];
  float* rrow = r + (size_t)token * D_;
  float4 rv[4];
#pragma unroll
  for (int q = 0; q < 4; q++) rv[q] = *(const float4*)(rrow + sub * 16 + q * 4);

  float dots[6];
#pragma unroll
  for (int i = 0; i < 6; i++) {
    const float* sr = es_k + (size_t)c6[i] * D_ + sub * 16;
    float a = 0.f;
#pragma unroll
    for (int q = 0; q < 4; q++) {
      float4 sv = *(const float4*)(sr + q * 4);
      a += rv[q].x * sv.x + rv[q].y * sv.y + rv[q].z * sv.z + rv[q].w * sv.w;
    }
    dots[i] = a;
  }
#pragma unroll
  for (int st = 1; st < 16; st <<= 1) {
#pragma unroll
    for (int i = 0; i < 6; i++) dots[i] += __shfl_xor(dots[i], st);
  }

  float bs = FLT_MAX, b2 = FLT_MAX; int bn = 0x7fffffff, bn2 = 0x7fffffff;
#pragma unroll
  for (int i = 0; i < 6; i++) {
    int n = c6[i];
    float s = nrm_k[n] - 2.0f * inv_k[n] * dots[i];
    bool better = (s < bs) || (s == bs && n < bn);
    bool second = (s < b2) || (s == b2 && n < bn2);
    if (better)      { b2 = bs; bn2 = bn; bs = s; bn = n; }
    else if (second) { b2 = s;  bn2 = n; }
  }
  int winner = bn;
  if (b2 - bs < 0.5f && bn2 != bn) {
    double sc[2]; int nn[2] = { bn, bn2 };
#pragma unroll
    for (int cI = 0; cI < 2; cI++) {
      double u = fmax((double)us_k[nn[cI]], 1e-5);
      double uinv = 1.0 / u;
      const float* srow = es_k + (size_t)nn[cI] * D_;
      double dotre = 0.0, ee = 0.0;
      for (int d = 0; d < D_; d++) {
        double e = (double)srow[d] * uinv;
        dotre += (double)rrow[d] * e;
        ee += e * e;
      }
      sc[cI] = ee - 2.0 * dotre;
    }
    if (sc[1] < sc[0] || (sc[1] == sc[0] && nn[1] < nn[0])) winner = nn[1];
  }

  float um = fmaxf(us_k[winner], EPSF);
  const float* sw = es_k + (size_t)winner * D_ + sub * 16;
#pragma unroll
  for (int q = 0; q < 4; q++) {
    float4 sv = *(const float4*)(sw + q * 4);
    rv[q].x -= sv.x / um; rv[q].y -= sv.y / um;
    rv[q].z -= sv.z / um; rv[q].w -= sv.w / um;
    *(float4*)(rrow + sub * 16 + q * 4) = rv[q];
  }
  if (sub == 0) codes_f[(size_t)k * BT + token] = (float)winner;
}

// ---------------------------------------------------------------------------
extern "C" void kernel_launch(void* const* d_in, const int* in_sizes, int n_in,
                              void* d_out, int out_size, void* d_ws, size_t ws_size,
                              hipStream_t stream) {
  const float* emb       = (const float*)d_in[0];
  const float* w_in      = (const float*)d_in[1];
  const float* w_out     = (const float*)d_in[2];
  const float* embed_sum = (const float*)d_in[3];
  const float* usage     = (const float*)d_in[4];

  float* outp    = (float*)d_out;
  float* codes_f = outp;
  float* proj_o  = outp + (size_t)K_ * BT;

  float* rb   = (float*)d_ws;                          // BT*D f32 (33.55 MB)
  float* inv  = rb + (size_t)BT * D_;                  // K*N
  float* nrm  = inv + (size_t)K_ * N_;                 // K*N
  int*   cand = (int*)(nrm + (size_t)K_ * N_);         // BT*6 ints
  _Float16* ehs = (_Float16*)(cand + (size_t)BT * 6);  // K*N*D f16 (8.39 MB)
  v8h* afragX = (v8h*)(ehs + (size_t)K_ * N_ * D_);    // 16*16*64*2 (512 KB)
  float* wc   = (float*)(afragX + 16 * 16 * 64 * 2);   // 512*512 f32 (1 MB)
  v8h* afragO = (v8h*)(wc + 512 * 512);                // 32*24*64*2 (1.5 MB)

  hipLaunchKernelGGL(wprep_x_kernel, dim3(256), dim3(64), 0, stream, w_in, afragX);
  hipLaunchKernelGGL(wc_kernel, dim3(1024), dim3(256), 0, stream, w_out, w_in, wc);
  hipLaunchKernelGGL(wprep_o_kernel, dim3(768), dim3(64), 0, stream, wc, w_out, afragO);
  hipLaunchKernelGGL(prep_kernel, dim3(K_ * N_ / 4), dim3(256), 0, stream,
                     embed_sum, usage, inv, nrm, ehs);
  hipLaunchKernelGGL(proj_x_kernel, dim3(BT / 64), dim3(256), 0, stream,
                     emb, afragX, rb);
  for (int k = 0; k < K_; k++) {
    hipLaunchKernelGGL(scan_kernel, dim3(256), dim3(512), 0, stream,
                       ehs, nrm, rb, cand, k);
    hipLaunchKernelGGL(select_kernel, dim3(BT / 16), dim3(256), 0, stream,
                       embed_sum, usage, inv, nrm, cand, rb, codes_f, k);
  }
  hipLaunchKernelGGL(proj_out_kernel, dim3(BT / 64), dim3(256), 0, stream,
                     emb, rb, afragO, proj_o);
}

// Round 5
// 1099.029 us; speedup vs baseline: 15.3888x; 1.2739x over previous
//
#include <hip/hip_runtime.h>
#include <float.h>
#include <math.h>

#define EPSF 1e-5f
#define NRM_BIAS 2048.0f

constexpr int B_  = 8;
constexpr int CIN = 512;
constexpr int T_  = 4096;
constexpr int K_  = 8;
constexpr int N_  = 2048;
constexpr int D_  = 256;
constexpr int BT  = B_ * T_;          // 32768 tokens

typedef _Float16 v8h __attribute__((ext_vector_type(8)));
typedef _Float16 v4h __attribute__((ext_vector_type(4)));
typedef float    v4f __attribute__((ext_vector_type(4)));

static __device__ __forceinline__ unsigned umn(unsigned a, unsigned b) { return a < b ? a : b; }
static __device__ __forceinline__ unsigned umx(unsigned a, unsigned b) { return a > b ? a : b; }

// ---------------------------------------------------------------------------
// prep: inv = 1/clamp(u), nrm = sum_d e^2 + NRM_BIAS (bias makes scan scores
// positive so float bits sort as u32); writes f16 codebook in MFMA-B-fragment
// swizzled order (proven round-2 kernel otherwise unchanged).
// ---------------------------------------------------------------------------
__global__ void __launch_bounds__(256) prep_kernel(const float* __restrict__ embed_sum,
                                                   const float* __restrict__ usage,
                                                   float* __restrict__ inv,
                                                   float* __restrict__ nrm,
                                                   _Float16* __restrict__ ehs) {
  int w    = threadIdx.x >> 6;
  int lane = threadIdx.x & 63;
  int kn   = blockIdx.x * 4 + w;
  int k    = kn >> 11, n = kn & (N_ - 1);
  const float* s = embed_sum + (size_t)kn * D_;
  float um = fmaxf(usage[kn], EPSF);
  float4 sv = *(const float4*)(s + lane * 4);
  float e0 = sv.x / um, e1 = sv.y / um, e2 = sv.z / um, e3 = sv.w / um;
  float v = e0 * e0 + e1 * e1 + e2 * e2 + e3 * e3;

  int half = n >> 10, chunk = (n >> 4) & 63, r = n & 15;
  int cg = lane >> 1, sub = lane & 1;
  v4h h4; h4[0] = (_Float16)e0; h4[1] = (_Float16)e1;
  h4[2] = (_Float16)e2; h4[3] = (_Float16)e3;
  size_t off16 = ((size_t)((k * 2 + half) * 64 + chunk)) * 4096
               + (size_t)(cg * 16 + r) * 8 + (size_t)sub * 4;
  *(v4h*)(ehs + off16) = h4;

  for (int off = 32; off > 0; off >>= 1) v += __shfl_down(v, off);
  if (lane == 0) { inv[kn] = 1.0f / um; nrm[kn] = v + NRM_BIAS; }
}

// ---------------------------------------------------------------------------
// wprep_x: w_in [D][CIN] -> hi/lo f16 fragments (unchanged).
// ---------------------------------------------------------------------------
__global__ void __launch_bounds__(64) wprep_x_kernel(const float* __restrict__ w_in,
                                                     v8h* __restrict__ afragX) {
  int lane = threadIdx.x;
  int mt = blockIdx.x >> 4, kstep = blockIdx.x & 15;
  int m = mt * 16 + (lane & 15), k0 = kstep * 32 + (lane >> 4) * 8;
  const float* src = w_in + (size_t)m * CIN + k0;
  float4 f0 = *(const float4*)src, f1 = *(const float4*)(src + 4);
  float e[8] = {f0.x, f0.y, f0.z, f0.w, f1.x, f1.y, f1.z, f1.w};
  v8h h, l;
#pragma unroll
  for (int j = 0; j < 8; j++) {
    _Float16 hh = (_Float16)e[j];
    h[j] = hh; l[j] = (_Float16)(e[j] - (float)hh);
  }
  v8h* dst = afragX + ((size_t)blockIdx.x * 64 + lane) * 2;
  dst[0] = h; dst[1] = l;
}

// ---------------------------------------------------------------------------
// wc: Wc[c][c'] = sum_d w_out[c][d] * w_in[d][c']   (fp32, 512x512, unchanged)
// ---------------------------------------------------------------------------
__global__ void __launch_bounds__(256) wc_kernel(const float* __restrict__ w_out,
                                                 const float* __restrict__ w_in,
                                                 float* __restrict__ wc) {
  int c  = blockIdx.x >> 1;
  int cp = (blockIdx.x & 1) * 256 + threadIdx.x;
  float acc = 0.f;
  for (int d = 0; d < D_; d++)
    acc += w_out[(size_t)c * D_ + d] * w_in[(size_t)d * CIN + cp];
  wc[(size_t)c * CIN + cp] = acc;
}

// ---------------------------------------------------------------------------
// wprep_o: combined A matrix [512 c][768 k] -> hi/lo f16 frags (unchanged;
// proj_out now consumes only the hi frag).
// ---------------------------------------------------------------------------
__global__ void __launch_bounds__(64) wprep_o_kernel(const float* __restrict__ wc,
                                                     const float* __restrict__ w_out,
                                                     v8h* __restrict__ afragO) {
  int lane = threadIdx.x;
  int mt = blockIdx.x / 24, kstep = blockIdx.x % 24;
  int m = mt * 16 + (lane & 15), k0 = kstep * 32 + (lane >> 4) * 8;
  float e[8];
  if (k0 < CIN) {
    const float* s = wc + (size_t)m * CIN + k0;
#pragma unroll
    for (int j = 0; j < 8; j++) e[j] = s[j];
  } else {
    const float* s = w_out + (size_t)m * D_ + (k0 - CIN);
#pragma unroll
    for (int j = 0; j < 8; j++) e[j] = -s[j];
  }
  v8h h, l;
#pragma unroll
  for (int j = 0; j < 8; j++) {
    _Float16 hh = (_Float16)e[j];
    h[j] = hh; l[j] = (_Float16)(e[j] - (float)hh);
  }
  v8h* dst = afragO + ((size_t)blockIdx.x * 64 + lane) * 2;
  dst[0] = h; dst[1] = l;
}

// ---------------------------------------------------------------------------
// proj_x: split-3 f16 MFMA (precision-critical: feeds RVQ codes; unchanged).
// ---------------------------------------------------------------------------
__global__ void __launch_bounds__(256, 2) proj_x_kernel(const float* __restrict__ emb,
                                                        const v8h* __restrict__ afragX,
                                                        float* __restrict__ rb) {
  int tid = threadIdx.x, wave = tid >> 6, lane = tid & 63;
  int lr = lane & 15, lg = lane >> 4;
  int t0 = blockIdx.x * 64 + wave * 16;
  int b  = t0 >> 12;
  const float* ebase = emb + (size_t)b * CIN * T_ + (t0 & (T_ - 1)) + lr;

  v4f acc[16];
#pragma unroll
  for (int nt = 0; nt < 16; nt++) acc[nt] = (v4f){0.f, 0.f, 0.f, 0.f};

  for (int ks = 0; ks < 16; ks++) {
    float e[8];
#pragma unroll
    for (int j = 0; j < 8; j++)
      e[j] = ebase[(size_t)(ks * 32 + lg * 8 + j) * T_];
    v8h Eh, El;
#pragma unroll
    for (int j = 0; j < 8; j++) {
      _Float16 hh = (_Float16)e[j];
      Eh[j] = hh; El[j] = (_Float16)(e[j] - (float)hh);
    }
    const v8h* ap = afragX + ((size_t)ks * 64 + lane) * 2;
#pragma unroll
    for (int nt = 0; nt < 16; nt++) {
      v8h Wh = ap[(size_t)nt * 2048];
      v8h Wl = ap[(size_t)nt * 2048 + 1];
      acc[nt] = __builtin_amdgcn_mfma_f32_16x16x32_f16(Eh, Wh, acc[nt], 0, 0, 0);
      acc[nt] = __builtin_amdgcn_mfma_f32_16x16x32_f16(El, Wh, acc[nt], 0, 0, 0);
      acc[nt] = __builtin_amdgcn_mfma_f32_16x16x32_f16(Eh, Wl, acc[nt], 0, 0, 0);
    }
  }
#pragma unroll
  for (int nt = 0; nt < 16; nt++)
#pragma unroll
    for (int r = 0; r < 4; r++)
      rb[(size_t)(t0 + lg * 4 + r) * D_ + nt * 16 + lr] = acc[nt][r];
}

// ---------------------------------------------------------------------------
// proj_out: single-f16-MFMA (out threshold 40.96 >> f16 error ~1e-3),
// m-split into 2 blocks (16 mt each) -> grid 1024, 4 blocks/CU, acc=64 VGPR.
// ---------------------------------------------------------------------------
__global__ void __launch_bounds__(256, 4) proj_out_kernel(const float* __restrict__ emb,
                                                          const float* __restrict__ rb,
                                                          const v8h* __restrict__ afragO,
                                                          float* __restrict__ outb) {
  int tid = threadIdx.x, wave = tid >> 6, lane = tid & 63;
  int lr = lane & 15, lg = lane >> 4;
  int tb = blockIdx.x >> 1, mb = blockIdx.x & 1;
  int t0 = tb * 64 + wave * 16;
  int b  = t0 >> 12;
  const float* ebase = emb + (size_t)b * CIN * T_ + (t0 & (T_ - 1)) + lr;

  v4f acc[16];
#pragma unroll
  for (int mt = 0; mt < 16; mt++) acc[mt] = (v4f){0.f, 0.f, 0.f, 0.f};

  for (int ks = 0; ks < 24; ks++) {
    float e[8];
    if (ks < 16) {
#pragma unroll
      for (int j = 0; j < 8; j++)
        e[j] = ebase[(size_t)(ks * 32 + lg * 8 + j) * T_];
    } else {
      const float* rrow = rb + (size_t)(t0 + lr) * D_ + (ks - 16) * 32 + lg * 8;
      float4 f0 = *(const float4*)rrow, f1 = *(const float4*)(rrow + 4);
      e[0] = f0.x; e[1] = f0.y; e[2] = f0.z; e[3] = f0.w;
      e[4] = f1.x; e[5] = f1.y; e[6] = f1.z; e[7] = f1.w;
    }
    v8h Bh;
#pragma unroll
    for (int j = 0; j < 8; j++) Bh[j] = (_Float16)e[j];
#pragma unroll
    for (int mt = 0; mt < 16; mt++) {
      v8h Ah = afragO[(((size_t)(mb * 16 + mt) * 24 + ks) * 64 + lane) * 2];
      acc[mt] = __builtin_amdgcn_mfma_f32_16x16x32_f16(Ah, Bh, acc[mt], 0, 0, 0);
    }
  }
  float* op = outb + (size_t)b * CIN * T_ + (t0 & (T_ - 1)) + lr;
#pragma unroll
  for (int mt = 0; mt < 16; mt++)
#pragma unroll
    for (int r = 0; r < 4; r++)
      op[(size_t)((mb * 16 + mt) * 16 + lg * 4 + r) * T_] = acc[mt][r];
}

// ---------------------------------------------------------------------------
// MFMA scan: 128-token groups (8 waves x 16 tokens), grid 512 (256 tg x 2
// half). Top-3 per token via packed sortable-u32 (score bits | 6-bit chunk):
// 5 min/max ops per insert instead of a cndmask chain.  Candidates exactly
// rescored downstream, so the <=0.016 packing quantization is safe.
// ---------------------------------------------------------------------------
__global__ void __launch_bounds__(512) scan_kernel(const _Float16* __restrict__ ehs,
                                                   const float* __restrict__ nrm,
                                                   const float* __restrict__ rb,
                                                   int* __restrict__ cand, int k) {
  __shared__ v8h ldsB[2][512];
  int tid  = threadIdx.x;
  int wave = tid >> 6, lane = tid & 63;
  int lr = lane & 15, lg = lane >> 4;
  int tg = blockIdx.x >> 1, half = blockIdx.x & 1;
  int wbase = tg * 128 + wave * 16;

  // A fragments: lane holds token (wbase + lr), k = c*32 + lg*8 + j
  v8h A[8];
  {
    const float* rrow = rb + (size_t)(wbase + lr) * D_;
#pragma unroll
    for (int c = 0; c < 8; c++) {
      int k0 = c * 32 + lg * 8;
      float4 f0 = *(const float4*)(rrow + k0);
      float4 f1 = *(const float4*)(rrow + k0 + 4);
      v8h a;
      a[0] = (_Float16)f0.x; a[1] = (_Float16)f0.y;
      a[2] = (_Float16)f0.z; a[3] = (_Float16)f0.w;
      a[4] = (_Float16)f1.x; a[5] = (_Float16)f1.y;
      a[6] = (_Float16)f1.z; a[7] = (_Float16)f1.w;
      A[c] = a;
    }
  }

  const v8h* src = (const v8h*)(ehs + ((size_t)(k * 2 + half)) * (64 * 4096));
  ldsB[0][tid] = src[tid];

  unsigned b1[4], b2[4], b3[4];
#pragma unroll
  for (int i = 0; i < 4; i++) { b1[i] = b2[i] = b3[i] = 0xFFFFFFFFu; }
  const float* nrm_k = nrm + (size_t)k * N_;
  __syncthreads();

  for (int ch = 0; ch < 64; ch++) {
    int cur = ch & 1;
    v8h nxt;
    bool more = (ch + 1 < 64);
    if (more) nxt = src[(size_t)(ch + 1) * 512 + tid];   // issue early (T14)

    v4f acc = {0.f, 0.f, 0.f, 0.f};
#pragma unroll
    for (int c = 0; c < 8; c++) {
      v8h Bf = ldsB[cur][(c * 4 + lg) * 16 + lr];
      acc = __builtin_amdgcn_mfma_f32_16x16x32_f16(A[c], Bf, acc, 0, 0, 0);
    }
    float nv = nrm_k[half * 1024 + ch * 16 + lr];   // biased +2048 -> s > 0
#pragma unroll
    for (int j = 0; j < 4; j++) {
      float s = fmaf(-2.0f, acc[j], nv);
      unsigned p = (__float_as_uint(s) & 0xFFFFFFC0u) | (unsigned)ch;
      unsigned m1 = umx(b1[j], p);  b1[j] = umn(b1[j], p);
      unsigned m2 = umx(b2[j], m1); b2[j] = umn(b2[j], m1);
      b3[j] = umn(b3[j], m2);
    }
    if (more) ldsB[cur ^ 1][tid] = nxt;   // write-late, other buffer
    __syncthreads();
  }

  // merge top-3 across the 16 lr-lanes of each row j (3x extract-min)
#pragma unroll
  for (int rI = 0; rI < 4; rI++) {
    unsigned k1 = b1[rI], k2 = b2[rI], k3 = b3[rI];
    int n1 = half * 1024 + (int)(k1 & 63u) * 16 + lr;
    int n2 = half * 1024 + (int)(k2 & 63u) * 16 + lr;
    int n3 = half * 1024 + (int)(k3 & 63u) * 16 + lr;
    int o0 = 0, o1 = 0, o2v = 0;
#pragma unroll
    for (int round = 0; round < 3; round++) {
      unsigned mk = k1; int mn = n1;
#pragma unroll
      for (int st = 1; st < 16; st <<= 1) {
        unsigned ok = (unsigned)__shfl_xor((int)mk, st);
        int      on = __shfl_xor(mn, st);
        bool t = (ok < mk) || (ok == mk && on < mn);
        mk = t ? ok : mk; mn = t ? on : mn;
      }
      if (round == 0) o0 = mn; else if (round == 1) o1 = mn; else o2v = mn;
      bool own = (k1 == mk) && (n1 == mn);
      k1 = own ? k2 : k1; n1 = own ? n2 : n1;
      k2 = own ? k3 : k2; n2 = own ? n3 : n2;
      k3 = own ? 0xFFFFFFFFu : k3; n3 = own ? 0x7fffffff : n3;
    }
    if (lr == 0) {
      int token = wbase + lg * 4 + rI;
      int* cp = cand + (size_t)token * 6 + half * 3;
      cp[0] = o0; cp[1] = o1; cp[2] = o2v;
    }
  }
}

// ---------------------------------------------------------------------------
// select (proven kernel, unchanged; nrm bias shifts all 6 scores equally)
// ---------------------------------------------------------------------------
__global__ void __launch_bounds__(256) select_kernel(const float* __restrict__ embed_sum,
                                                     const float* __restrict__ usage,
                                                     const float* __restrict__ inv_,
                                                     const float* __restrict__ nrm,
                                                     const int* __restrict__ cand,
                                                     float* __restrict__ r,
                                                     float* __restrict__ codes_f, int k) {
  int tid = threadIdx.x;
  int sub = tid & 15, g = tid >> 4;
  int token = blockIdx.x * 16 + g;
  const float* es_k  = embed_sum + (size_t)k * N_ * D_;
  const float* us_k  = usage + (size_t)k * N_;
  const float* inv_k = inv_  + (size_t)k * N_;
  const float* nrm_k = nrm   + (size_t)k * N_;

  int c6[6];
#pragma unroll
  for (int i = 0; i < 6; i++) c6[i] = cand[(size_t)token * 6 + i];
  float* rrow = r + (size_t)token * D_;
  float4 rv[4];
#pragma unroll
  for (int q = 0; q < 4; q++) rv[q] = *(const float4*)(rrow + sub * 16 + q * 4);

  float dots[6];
#pragma unroll
  for (int i = 0; i < 6; i++) {
    const float* sr = es_k + (size_t)c6[i] * D_ + sub * 16;
    float a = 0.f;
#pragma unroll
    for (int q = 0; q < 4; q++) {
      float4 sv = *(const float4*)(sr + q * 4);
      a += rv[q].x * sv.x + rv[q].y * sv.y + rv[q].z * sv.z + rv[q].w * sv.w;
    }
    dots[i] = a;
  }
#pragma unroll
  for (int st = 1; st < 16; st <<= 1) {
#pragma unroll
    for (int i = 0; i < 6; i++) dots[i] += __shfl_xor(dots[i], st);
  }

  float bs = FLT_MAX, b2 = FLT_MAX; int bn = 0x7fffffff, bn2 = 0x7fffffff;
#pragma unroll
  for (int i = 0; i < 6; i++) {
    int n = c6[i];
    float s = nrm_k[n] - 2.0f * inv_k[n] * dots[i];
    bool better = (s < bs) || (s == bs && n < bn);
    bool second = (s < b2) || (s == b2 && n < bn2);
    if (better)      { b2 = bs; bn2 = bn; bs = s; bn = n; }
    else if (second) { b2 = s;  bn2 = n; }
  }
  int winner = bn;
  if (b2 - bs < 0.5f && bn2 != bn) {
    double sc[2]; int nn[2] = { bn, bn2 };
#pragma unroll
    for (int cI = 0; cI < 2; cI++) {
      double u = fmax((double)us_k[nn[cI]], 1e-5);
      double uinv = 1.0 / u;
      const float* srow = es_k + (size_t)nn[cI] * D_;
      double dotre = 0.0, ee = 0.0;
      for (int d = 0; d < D_; d++) {
        double e = (double)srow[d] * uinv;
        dotre += (double)rrow[d] * e;
        ee += e * e;
      }
      sc[cI] = ee - 2.0 * dotre;
    }
    if (sc[1] < sc[0] || (sc[1] == sc[0] && nn[1] < nn[0])) winner = nn[1];
  }

  float um = fmaxf(us_k[winner], EPSF);
  const float* sw = es_k + (size_t)winner * D_ + sub * 16;
#pragma unroll
  for (int q = 0; q < 4; q++) {
    float4 sv = *(const float4*)(sw + q * 4);
    rv[q].x -= sv.x / um; rv[q].y -= sv.y / um;
    rv[q].z -= sv.z / um; rv[q].w -= sv.w / um;
    *(float4*)(rrow + sub * 16 + q * 4) = rv[q];
  }
  if (sub == 0) codes_f[(size_t)k * BT + token] = (float)winner;
}

// ---------------------------------------------------------------------------
extern "C" void kernel_launch(void* const* d_in, const int* in_sizes, int n_in,
                              void* d_out, int out_size, void* d_ws, size_t ws_size,
                              hipStream_t stream) {
  const float* emb       = (const float*)d_in[0];
  const float* w_in      = (const float*)d_in[1];
  const float* w_out     = (const float*)d_in[2];
  const float* embed_sum = (const float*)d_in[3];
  const float* usage     = (const float*)d_in[4];

  float* outp    = (float*)d_out;
  float* codes_f = outp;
  float* proj_o  = outp + (size_t)K_ * BT;

  float* rb   = (float*)d_ws;                          // BT*D f32 (33.55 MB)
  float* inv  = rb + (size_t)BT * D_;                  // K*N
  float* nrm  = inv + (size_t)K_ * N_;                 // K*N
  int*   cand = (int*)(nrm + (size_t)K_ * N_);         // BT*6 ints
  _Float16* ehs = (_Float16*)(cand + (size_t)BT * 6);  // K*N*D f16 (8.39 MB)
  v8h* afragX = (v8h*)(ehs + (size_t)K_ * N_ * D_);    // 512 KB
  float* wc   = (float*)(afragX + 16 * 16 * 64 * 2);   // 1 MB
  v8h* afragO = (v8h*)(wc + 512 * 512);                // 1.5 MB

  hipLaunchKernelGGL(wprep_x_kernel, dim3(256), dim3(64), 0, stream, w_in, afragX);
  hipLaunchKernelGGL(wc_kernel, dim3(1024), dim3(256), 0, stream, w_out, w_in, wc);
  hipLaunchKernelGGL(wprep_o_kernel, dim3(768), dim3(64), 0, stream, wc, w_out, afragO);
  hipLaunchKernelGGL(prep_kernel, dim3(K_ * N_ / 4), dim3(256), 0, stream,
                     embed_sum, usage, inv, nrm, ehs);
  hipLaunchKernelGGL(proj_x_kernel, dim3(BT / 64), dim3(256), 0, stream,
                     emb, afragX, rb);
  for (int k = 0; k < K_; k++) {
    hipLaunchKernelGGL(scan_kernel, dim3(512), dim3(512), 0, stream,
                       ehs, nrm, rb, cand, k);
    hipLaunchKernelGGL(select_kernel, dim3(BT / 16), dim3(256), 0, stream,
                       embed_sum, usage, inv, nrm, cand, rb, codes_f, k);
  }
  hipLaunchKernelGGL(proj_out_kernel, dim3(BT / 32), dim3(256), 0, stream,
                     emb, rb, afragO, proj_o);
}

// Round 6
// 997.357 us; speedup vs baseline: 16.9576x; 1.1019x over previous
//
#include <hip/hip_runtime.h>
#include <float.h>
#include <math.h>

#define EPSF 1e-5f
#define NRM_BIAS 2048.0f

constexpr int B_  = 8;
constexpr int CIN = 512;
constexpr int T_  = 4096;
constexpr int K_  = 8;
constexpr int N_  = 2048;
constexpr int D_  = 256;
constexpr int BT  = B_ * T_;          // 32768 tokens

typedef _Float16 v8h __attribute__((ext_vector_type(8)));
typedef _Float16 v4h __attribute__((ext_vector_type(4)));
typedef float    v4f __attribute__((ext_vector_type(4)));

static __device__ __forceinline__ unsigned umn(unsigned a, unsigned b) { return a < b ? a : b; }
static __device__ __forceinline__ unsigned umx(unsigned a, unsigned b) { return a > b ? a : b; }

// ---------------------------------------------------------------------------
// prep: inv = 1/clamp(u), nrm = sum_d e^2 + NRM_BIAS; f16 codebook in
// MFMA-B-fragment-swizzled order (proven, unchanged).
// ---------------------------------------------------------------------------
__global__ void __launch_bounds__(256) prep_kernel(const float* __restrict__ embed_sum,
                                                   const float* __restrict__ usage,
                                                   float* __restrict__ inv,
                                                   float* __restrict__ nrm,
                                                   _Float16* __restrict__ ehs) {
  int w    = threadIdx.x >> 6;
  int lane = threadIdx.x & 63;
  int kn   = blockIdx.x * 4 + w;
  int k    = kn >> 11, n = kn & (N_ - 1);
  const float* s = embed_sum + (size_t)kn * D_;
  float um = fmaxf(usage[kn], EPSF);
  float4 sv = *(const float4*)(s + lane * 4);
  float e0 = sv.x / um, e1 = sv.y / um, e2 = sv.z / um, e3 = sv.w / um;
  float v = e0 * e0 + e1 * e1 + e2 * e2 + e3 * e3;

  int half = n >> 10, chunk = (n >> 4) & 63, r = n & 15;
  int cg = lane >> 1, sub = lane & 1;
  v4h h4; h4[0] = (_Float16)e0; h4[1] = (_Float16)e1;
  h4[2] = (_Float16)e2; h4[3] = (_Float16)e3;
  size_t off16 = ((size_t)((k * 2 + half) * 64 + chunk)) * 4096
               + (size_t)(cg * 16 + r) * 8 + (size_t)sub * 4;
  *(v4h*)(ehs + off16) = h4;

  for (int off = 32; off > 0; off >>= 1) v += __shfl_down(v, off);
  if (lane == 0) { inv[kn] = 1.0f / um; nrm[kn] = v + NRM_BIAS; }
}

// ---------------------------------------------------------------------------
// wprep_x / wc / wprep_o (proven, unchanged)
// ---------------------------------------------------------------------------
__global__ void __launch_bounds__(64) wprep_x_kernel(const float* __restrict__ w_in,
                                                     v8h* __restrict__ afragX) {
  int lane = threadIdx.x;
  int mt = blockIdx.x >> 4, kstep = blockIdx.x & 15;
  int m = mt * 16 + (lane & 15), k0 = kstep * 32 + (lane >> 4) * 8;
  const float* src = w_in + (size_t)m * CIN + k0;
  float4 f0 = *(const float4*)src, f1 = *(const float4*)(src + 4);
  float e[8] = {f0.x, f0.y, f0.z, f0.w, f1.x, f1.y, f1.z, f1.w};
  v8h h, l;
#pragma unroll
  for (int j = 0; j < 8; j++) {
    _Float16 hh = (_Float16)e[j];
    h[j] = hh; l[j] = (_Float16)(e[j] - (float)hh);
  }
  v8h* dst = afragX + ((size_t)blockIdx.x * 64 + lane) * 2;
  dst[0] = h; dst[1] = l;
}

__global__ void __launch_bounds__(256) wc_kernel(const float* __restrict__ w_out,
                                                 const float* __restrict__ w_in,
                                                 float* __restrict__ wc) {
  int c  = blockIdx.x >> 1;
  int cp = (blockIdx.x & 1) * 256 + threadIdx.x;
  float acc = 0.f;
  for (int d = 0; d < D_; d++)
    acc += w_out[(size_t)c * D_ + d] * w_in[(size_t)d * CIN + cp];
  wc[(size_t)c * CIN + cp] = acc;
}

__global__ void __launch_bounds__(64) wprep_o_kernel(const float* __restrict__ wc,
                                                     const float* __restrict__ w_out,
                                                     v8h* __restrict__ afragO) {
  int lane = threadIdx.x;
  int mt = blockIdx.x / 24, kstep = blockIdx.x % 24;
  int m = mt * 16 + (lane & 15), k0 = kstep * 32 + (lane >> 4) * 8;
  float e[8];
  if (k0 < CIN) {
    const float* s = wc + (size_t)m * CIN + k0;
#pragma unroll
    for (int j = 0; j < 8; j++) e[j] = s[j];
  } else {
    const float* s = w_out + (size_t)m * D_ + (k0 - CIN);
#pragma unroll
    for (int j = 0; j < 8; j++) e[j] = -s[j];
  }
  v8h h, l;
#pragma unroll
  for (int j = 0; j < 8; j++) {
    _Float16 hh = (_Float16)e[j];
    h[j] = hh; l[j] = (_Float16)(e[j] - (float)hh);
  }
  v8h* dst = afragO + ((size_t)blockIdx.x * 64 + lane) * 2;
  dst[0] = h; dst[1] = l;
}

// ---------------------------------------------------------------------------
// proj_x: split-3 f16 MFMA, now m-split x2 (proj_out's proven occupancy fix):
// grid 1024, blk&1 selects d-half, acc 8 v4f.
// ---------------------------------------------------------------------------
__global__ void __launch_bounds__(256, 4) proj_x_kernel(const float* __restrict__ emb,
                                                        const v8h* __restrict__ afragX,
                                                        float* __restrict__ rb) {
  int tid = threadIdx.x, wave = tid >> 6, lane = tid & 63;
  int lr = lane & 15, lg = lane >> 4;
  int tb = blockIdx.x >> 1, nb = blockIdx.x & 1;
  int t0 = tb * 64 + wave * 16;
  int b  = t0 >> 12;
  const float* ebase = emb + (size_t)b * CIN * T_ + (t0 & (T_ - 1)) + lr;

  v4f acc[8];
#pragma unroll
  for (int nt = 0; nt < 8; nt++) acc[nt] = (v4f){0.f, 0.f, 0.f, 0.f};

  for (int ks = 0; ks < 16; ks++) {
    float e[8];
#pragma unroll
    for (int j = 0; j < 8; j++)
      e[j] = ebase[(size_t)(ks * 32 + lg * 8 + j) * T_];
    v8h Eh, El;
#pragma unroll
    for (int j = 0; j < 8; j++) {
      _Float16 hh = (_Float16)e[j];
      Eh[j] = hh; El[j] = (_Float16)(e[j] - (float)hh);
    }
    const v8h* ap = afragX + ((size_t)ks * 64 + lane) * 2;
#pragma unroll
    for (int nt = 0; nt < 8; nt++) {
      int mt = nb * 8 + nt;
      v8h Wh = ap[(size_t)mt * 2048];
      v8h Wl = ap[(size_t)mt * 2048 + 1];
      acc[nt] = __builtin_amdgcn_mfma_f32_16x16x32_f16(Eh, Wh, acc[nt], 0, 0, 0);
      acc[nt] = __builtin_amdgcn_mfma_f32_16x16x32_f16(El, Wh, acc[nt], 0, 0, 0);
      acc[nt] = __builtin_amdgcn_mfma_f32_16x16x32_f16(Eh, Wl, acc[nt], 0, 0, 0);
    }
  }
#pragma unroll
  for (int nt = 0; nt < 8; nt++)
#pragma unroll
    for (int r = 0; r < 4; r++)
      rb[(size_t)(t0 + lg * 4 + r) * D_ + (nb * 8 + nt) * 16 + lr] = acc[nt][r];
}

// ---------------------------------------------------------------------------
// proj_out (proven round-5 kernel, unchanged)
// ---------------------------------------------------------------------------
__global__ void __launch_bounds__(256, 4) proj_out_kernel(const float* __restrict__ emb,
                                                          const float* __restrict__ rb,
                                                          const v8h* __restrict__ afragO,
                                                          float* __restrict__ outb) {
  int tid = threadIdx.x, wave = tid >> 6, lane = tid & 63;
  int lr = lane & 15, lg = lane >> 4;
  int tb = blockIdx.x >> 1, mb = blockIdx.x & 1;
  int t0 = tb * 64 + wave * 16;
  int b  = t0 >> 12;
  const float* ebase = emb + (size_t)b * CIN * T_ + (t0 & (T_ - 1)) + lr;

  v4f acc[16];
#pragma unroll
  for (int mt = 0; mt < 16; mt++) acc[mt] = (v4f){0.f, 0.f, 0.f, 0.f};

  for (int ks = 0; ks < 24; ks++) {
    float e[8];
    if (ks < 16) {
#pragma unroll
      for (int j = 0; j < 8; j++)
        e[j] = ebase[(size_t)(ks * 32 + lg * 8 + j) * T_];
    } else {
      const float* rrow = rb + (size_t)(t0 + lr) * D_ + (ks - 16) * 32 + lg * 8;
      float4 f0 = *(const float4*)rrow, f1 = *(const float4*)(rrow + 4);
      e[0] = f0.x; e[1] = f0.y; e[2] = f0.z; e[3] = f0.w;
      e[4] = f1.x; e[5] = f1.y; e[6] = f1.z; e[7] = f1.w;
    }
    v8h Bh;
#pragma unroll
    for (int j = 0; j < 8; j++) Bh[j] = (_Float16)e[j];
#pragma unroll
    for (int mt = 0; mt < 16; mt++) {
      v8h Ah = afragO[(((size_t)(mb * 16 + mt) * 24 + ks) * 64 + lane) * 2];
      acc[mt] = __builtin_amdgcn_mfma_f32_16x16x32_f16(Ah, Bh, acc[mt], 0, 0, 0);
    }
  }
  float* op = outb + (size_t)b * CIN * T_ + (t0 & (T_ - 1)) + lr;
#pragma unroll
  for (int mt = 0; mt < 16; mt++)
#pragma unroll
    for (int r = 0; r < 4; r++)
      op[(size_t)((mb * 16 + mt) * 16 + lg * 4 + r) * T_] = acc[mt][r];
}

// ---------------------------------------------------------------------------
// merge helper: extract top-3 (packed u32, cg in low 7 bits) across the 16
// lr-lanes of each row, write to LDS candidate table.
// ---------------------------------------------------------------------------
__device__ __forceinline__ void merge_save(unsigned b1[4], unsigned b2[4], unsigned b3[4],
                                           int half, int wave, int lg, int lr,
                                           int (*candL)[6]) {
#pragma unroll
  for (int rI = 0; rI < 4; rI++) {
    unsigned k1 = b1[rI], k2 = b2[rI], k3 = b3[rI];
    int n1 = (int)(k1 & 127u) * 16 + lr;
    int n2 = (int)(k2 & 127u) * 16 + lr;
    int n3 = (int)(k3 & 127u) * 16 + lr;
    int o0 = 0, o1 = 0, o2v = 0;
#pragma unroll
    for (int round = 0; round < 3; round++) {
      unsigned mk = k1; int mn = n1;
#pragma unroll
      for (int st = 1; st < 16; st <<= 1) {
        unsigned ok = (unsigned)__shfl_xor((int)mk, st);
        int      on = __shfl_xor(mn, st);
        bool t = (ok < mk) || (ok == mk && on < mn);
        mk = t ? ok : mk; mn = t ? on : mn;
      }
      if (round == 0) o0 = mn; else if (round == 1) o1 = mn; else o2v = mn;
      bool own = (k1 == mk) && (n1 == mn);
      k1 = own ? k2 : k1; n1 = own ? n2 : n1;
      k2 = own ? k3 : k2; n2 = own ? n3 : n2;
      k3 = own ? 0xFFFFFFFFu : k3; n3 = own ? 0x7fffffff : n3;
    }
    if (lr == 0) {
      int* cp = candL[wave * 16 + lg * 4 + rI] + half * 3;
      cp[0] = o0; cp[1] = o1; cp[2] = o2v;
    }
  }
}

// ---------------------------------------------------------------------------
// Fused RVQ step: full-codebook MFMA scan (2 chunks/stage, per-half top-3,
// round-5 math) + in-kernel select (fp32 rescore of 6 candidates, fp64
// escalation, residual update).  Block: 512 thr = 8 waves x 16 tokens.
// ---------------------------------------------------------------------------
__global__ void __launch_bounds__(512) rvq_fused_kernel(const _Float16* __restrict__ ehs,
                                                        const float* __restrict__ nrm,
                                                        const float* __restrict__ inv_,
                                                        const float* __restrict__ usage,
                                                        const float* __restrict__ embed_sum,
                                                        float* __restrict__ rb,
                                                        float* __restrict__ codes_f, int k) {
  __shared__ v8h ldsB[2][1024];   // 32 KB: 2 buf x 2 chunks x 4096 f16
  __shared__ int candL[128][6];

  int tid  = threadIdx.x;
  int wave = tid >> 6, lane = tid & 63;
  int lr = lane & 15, lg = lane >> 4;
  int wbase = blockIdx.x * 128 + wave * 16;

  // A fragments: lane holds token (wbase + lr), k = c*32 + lg*8 + j
  v8h A[8];
  {
    const float* rrow = rb + (size_t)(wbase + lr) * D_;
#pragma unroll
    for (int c = 0; c < 8; c++) {
      int k0 = c * 32 + lg * 8;
      float4 f0 = *(const float4*)(rrow + k0);
      float4 f1 = *(const float4*)(rrow + k0 + 4);
      v8h a;
      a[0] = (_Float16)f0.x; a[1] = (_Float16)f0.y;
      a[2] = (_Float16)f0.z; a[3] = (_Float16)f0.w;
      a[4] = (_Float16)f1.x; a[5] = (_Float16)f1.y;
      a[6] = (_Float16)f1.z; a[7] = (_Float16)f1.w;
      A[c] = a;
    }
  }

  const v8h* src = (const v8h*)(ehs + (size_t)k * 2 * (64 * 4096));  // 128 chunks
  ldsB[0][tid]       = src[tid];
  ldsB[0][512 + tid] = src[512 + tid];

  unsigned b1[4], b2[4], b3[4];
#pragma unroll
  for (int i = 0; i < 4; i++) { b1[i] = b2[i] = b3[i] = 0xFFFFFFFFu; }
  const float* nrm_k = nrm + (size_t)k * N_;
  __syncthreads();

  for (int p = 0; p < 64; p++) {
    int cur = p & 1;
    v8h nxt0, nxt1;
    bool more = (p + 1 < 64);
    if (more) {
      nxt0 = src[(size_t)(p + 1) * 1024 + tid];        // issue early (T14)
      nxt1 = src[(size_t)(p + 1) * 1024 + 512 + tid];
    }

    v4f accA = {0.f, 0.f, 0.f, 0.f}, accB = {0.f, 0.f, 0.f, 0.f};
#pragma unroll
    for (int c = 0; c < 8; c++) {
      v8h BfA = ldsB[cur][(c * 4 + lg) * 16 + lr];
      v8h BfB = ldsB[cur][512 + (c * 4 + lg) * 16 + lr];
      accA = __builtin_amdgcn_mfma_f32_16x16x32_f16(A[c], BfA, accA, 0, 0, 0);
      accB = __builtin_amdgcn_mfma_f32_16x16x32_f16(A[c], BfB, accB, 0, 0, 0);
    }
    unsigned cgA = 2 * p, cgB = 2 * p + 1;
    float nvA = nrm_k[cgA * 16 + lr];                  // biased +2048 -> s > 0
    float nvB = nrm_k[cgB * 16 + lr];
#pragma unroll
    for (int j = 0; j < 4; j++) {
      {
        float s = fmaf(-2.0f, accA[j], nvA);
        unsigned pk = (__float_as_uint(s) & 0xFFFFFF80u) | cgA;
        unsigned t = umx(b1[j], pk);
        unsigned u = umx(b2[j], pk);   // == umx(b2, max(b1,pk)) since b1<=b2
        b1[j] = umn(b1[j], pk);
        b2[j] = umn(b2[j], t);
        b3[j] = umn(b3[j], u);
      }
      {
        float s = fmaf(-2.0f, accB[j], nvB);
        unsigned pk = (__float_as_uint(s) & 0xFFFFFF80u) | cgB;
        unsigned t = umx(b1[j], pk);
        unsigned u = umx(b2[j], pk);
        b1[j] = umn(b1[j], pk);
        b2[j] = umn(b2[j], t);
        b3[j] = umn(b3[j], u);
      }
    }
    if (more) {
      ldsB[cur ^ 1][tid]       = nxt0;                 // write-late, other buffer
      ldsB[cur ^ 1][512 + tid] = nxt1;
    }
    if (p == 31) {                                     // end of half 0
      merge_save(b1, b2, b3, 0, wave, lg, lr, candL);
#pragma unroll
      for (int i = 0; i < 4; i++) { b1[i] = b2[i] = b3[i] = 0xFFFFFFFFu; }
    }
    __syncthreads();
  }
  merge_save(b1, b2, b3, 1, wave, lg, lr, candL);
  __syncthreads();

  // -------- select phase: 4 lanes per token, 64 dims each --------
  int tt = tid >> 2, q = tid & 3;
  int token = blockIdx.x * 128 + tt;
  const float* es_k  = embed_sum + (size_t)k * N_ * D_;
  const float* us_k  = usage + (size_t)k * N_;
  const float* inv_k = inv_  + (size_t)k * N_;

  int c6[6];
#pragma unroll
  for (int i = 0; i < 6; i++) c6[i] = candL[tt][i];
  float* rrow = rb + (size_t)token * D_;
  float* rq = rrow + q * 64;
  float4 rv[16];
#pragma unroll
  for (int m = 0; m < 16; m++) rv[m] = *(const float4*)(rq + m * 4);

  float dots[6];
#pragma unroll
  for (int i = 0; i < 6; i++) {
    const float* sr = es_k + (size_t)c6[i] * D_ + q * 64;
    float a = 0.f;
#pragma unroll
    for (int m = 0; m < 16; m++) {
      float4 sv = *(const float4*)(sr + m * 4);
      a += rv[m].x * sv.x + rv[m].y * sv.y + rv[m].z * sv.z + rv[m].w * sv.w;
    }
    dots[i] = a;
  }
#pragma unroll
  for (int st = 1; st < 4; st <<= 1) {
#pragma unroll
    for (int i = 0; i < 6; i++) dots[i] += __shfl_xor(dots[i], st);
  }

  float bs = FLT_MAX, bv2 = FLT_MAX; int bn = 0x7fffffff, bn2 = 0x7fffffff;
#pragma unroll
  for (int i = 0; i < 6; i++) {
    int n = c6[i];
    float s = nrm_k[n] - 2.0f * inv_k[n] * dots[i];
    bool better = (s < bs) || (s == bs && n < bn);
    bool second = (s < bv2) || (s == bv2 && n < bn2);
    if (better)      { bv2 = bs; bn2 = bn; bs = s; bn = n; }
    else if (second) { bv2 = s;  bn2 = n; }
  }
  int winner = bn;
  if (bv2 - bs < 0.5f && bn2 != bn) {
    double sc[2]; int nn[2] = { bn, bn2 };
#pragma unroll
    for (int cI = 0; cI < 2; cI++) {
      double u = fmax((double)us_k[nn[cI]], 1e-5);
      double uinv = 1.0 / u;
      const float* srow = es_k + (size_t)nn[cI] * D_ + q * 64;
      double dotre = 0.0, ee = 0.0;
#pragma unroll
      for (int m = 0; m < 16; m++) {
        float4 sv = *(const float4*)(srow + m * 4);
        double e0 = (double)sv.x * uinv, e1 = (double)sv.y * uinv;
        double e2 = (double)sv.z * uinv, e3 = (double)sv.w * uinv;
        dotre += (double)rv[m].x * e0 + (double)rv[m].y * e1
               + (double)rv[m].z * e2 + (double)rv[m].w * e3;
        ee += e0 * e0 + e1 * e1 + e2 * e2 + e3 * e3;
      }
      dotre += __shfl_xor(dotre, 1); dotre += __shfl_xor(dotre, 2);
      ee    += __shfl_xor(ee, 1);    ee    += __shfl_xor(ee, 2);
      sc[cI] = ee - 2.0 * dotre;
    }
    if (sc[1] < sc[0] || (sc[1] == sc[0] && nn[1] < nn[0])) winner = nn[1];
  }

  float um = fmaxf(us_k[winner], EPSF);
  const float* sw = es_k + (size_t)winner * D_ + q * 64;
#pragma unroll
  for (int m = 0; m < 16; m++) {
    float4 sv = *(const float4*)(sw + m * 4);
    rv[m].x -= sv.x / um; rv[m].y -= sv.y / um;
    rv[m].z -= sv.z / um; rv[m].w -= sv.w / um;
    *(float4*)(rq + m * 4) = rv[m];
  }
  if (q == 0) codes_f[(size_t)k * BT + token] = (float)winner;
}

// ---------------------------------------------------------------------------
extern "C" void kernel_launch(void* const* d_in, const int* in_sizes, int n_in,
                              void* d_out, int out_size, void* d_ws, size_t ws_size,
                              hipStream_t stream) {
  const float* emb       = (const float*)d_in[0];
  const float* w_in      = (const float*)d_in[1];
  const float* w_out     = (const float*)d_in[2];
  const float* embed_sum = (const float*)d_in[3];
  const float* usage     = (const float*)d_in[4];

  float* outp    = (float*)d_out;
  float* codes_f = outp;
  float* proj_o  = outp + (size_t)K_ * BT;

  float* rb   = (float*)d_ws;                          // BT*D f32 (33.55 MB)
  float* inv  = rb + (size_t)BT * D_;                  // K*N
  float* nrm  = inv + (size_t)K_ * N_;                 // K*N
  int*   cand = (int*)(nrm + (size_t)K_ * N_);         // (unused gap, kept)
  _Float16* ehs = (_Float16*)(cand + (size_t)BT * 6);  // K*N*D f16 (8.39 MB)
  v8h* afragX = (v8h*)(ehs + (size_t)K_ * N_ * D_);    // 512 KB
  float* wc   = (float*)(afragX + 16 * 16 * 64 * 2);   // 1 MB
  v8h* afragO = (v8h*)(wc + 512 * 512);                // 1.5 MB

  hipLaunchKernelGGL(wprep_x_kernel, dim3(256), dim3(64), 0, stream, w_in, afragX);
  hipLaunchKernelGGL(wc_kernel, dim3(1024), dim3(256), 0, stream, w_out, w_in, wc);
  hipLaunchKernelGGL(wprep_o_kernel, dim3(768), dim3(64), 0, stream, wc, w_out, afragO);
  hipLaunchKernelGGL(prep_kernel, dim3(K_ * N_ / 4), dim3(256), 0, stream,
                     embed_sum, usage, inv, nrm, ehs);
  hipLaunchKernelGGL(proj_x_kernel, dim3(BT / 32), dim3(256), 0, stream,
                     emb, afragX, rb);
  for (int k = 0; k < K_; k++)
    hipLaunchKernelGGL(rvq_fused_kernel, dim3(BT / 128), dim3(512), 0, stream,
                       ehs, nrm, inv, usage, embed_sum, rb, codes_f, k);
  hipLaunchKernelGGL(proj_out_kernel, dim3(BT / 32), dim3(256), 0, stream,
                     emb, rb, afragO, proj_o);
}

// Round 7
// 894.074 us; speedup vs baseline: 18.9165x; 1.1155x over previous
//
#include <hip/hip_runtime.h>
#include <float.h>
#include <math.h>

#define EPSF 1e-5f
#define NRM_BIAS 2048.0f

constexpr int B_  = 8;
constexpr int CIN = 512;
constexpr int T_  = 4096;
constexpr int K_  = 8;
constexpr int N_  = 2048;
constexpr int D_  = 256;
constexpr int BT  = B_ * T_;          // 32768 tokens

typedef _Float16 v8h __attribute__((ext_vector_type(8)));
typedef _Float16 v4h __attribute__((ext_vector_type(4)));
typedef float    v4f __attribute__((ext_vector_type(4)));

static __device__ __forceinline__ unsigned umn(unsigned a, unsigned b) { return a < b ? a : b; }
static __device__ __forceinline__ unsigned umx(unsigned a, unsigned b) { return a > b ? a : b; }

// ---------------------------------------------------------------------------
// prep: inv = 1/clamp(u), nrm = sum_d e^2 + NRM_BIAS; f16 codebook in
// MFMA-B-fragment-swizzled order (proven, unchanged).
// ---------------------------------------------------------------------------
__global__ void __launch_bounds__(256) prep_kernel(const float* __restrict__ embed_sum,
                                                   const float* __restrict__ usage,
                                                   float* __restrict__ inv,
                                                   float* __restrict__ nrm,
                                                   _Float16* __restrict__ ehs) {
  int w    = threadIdx.x >> 6;
  int lane = threadIdx.x & 63;
  int kn   = blockIdx.x * 4 + w;
  int k    = kn >> 11, n = kn & (N_ - 1);
  const float* s = embed_sum + (size_t)kn * D_;
  float um = fmaxf(usage[kn], EPSF);
  float4 sv = *(const float4*)(s + lane * 4);
  float e0 = sv.x / um, e1 = sv.y / um, e2 = sv.z / um, e3 = sv.w / um;
  float v = e0 * e0 + e1 * e1 + e2 * e2 + e3 * e3;

  int half = n >> 10, chunk = (n >> 4) & 63, r = n & 15;
  int cg = lane >> 1, sub = lane & 1;
  v4h h4; h4[0] = (_Float16)e0; h4[1] = (_Float16)e1;
  h4[2] = (_Float16)e2; h4[3] = (_Float16)e3;
  size_t off16 = ((size_t)((k * 2 + half) * 64 + chunk)) * 4096
               + (size_t)(cg * 16 + r) * 8 + (size_t)sub * 4;
  *(v4h*)(ehs + off16) = h4;

  for (int off = 32; off > 0; off >>= 1) v += __shfl_down(v, off);
  if (lane == 0) { inv[kn] = 1.0f / um; nrm[kn] = v + NRM_BIAS; }
}

// ---------------------------------------------------------------------------
// wprep_x / wc / wprep_o (proven, unchanged)
// ---------------------------------------------------------------------------
__global__ void __launch_bounds__(64) wprep_x_kernel(const float* __restrict__ w_in,
                                                     v8h* __restrict__ afragX) {
  int lane = threadIdx.x;
  int mt = blockIdx.x >> 4, kstep = blockIdx.x & 15;
  int m = mt * 16 + (lane & 15), k0 = kstep * 32 + (lane >> 4) * 8;
  const float* src = w_in + (size_t)m * CIN + k0;
  float4 f0 = *(const float4*)src, f1 = *(const float4*)(src + 4);
  float e[8] = {f0.x, f0.y, f0.z, f0.w, f1.x, f1.y, f1.z, f1.w};
  v8h h, l;
#pragma unroll
  for (int j = 0; j < 8; j++) {
    _Float16 hh = (_Float16)e[j];
    h[j] = hh; l[j] = (_Float16)(e[j] - (float)hh);
  }
  v8h* dst = afragX + ((size_t)blockIdx.x * 64 + lane) * 2;
  dst[0] = h; dst[1] = l;
}

__global__ void __launch_bounds__(256) wc_kernel(const float* __restrict__ w_out,
                                                 const float* __restrict__ w_in,
                                                 float* __restrict__ wc) {
  int c  = blockIdx.x >> 1;
  int cp = (blockIdx.x & 1) * 256 + threadIdx.x;
  float acc = 0.f;
  for (int d = 0; d < D_; d++)
    acc += w_out[(size_t)c * D_ + d] * w_in[(size_t)d * CIN + cp];
  wc[(size_t)c * CIN + cp] = acc;
}

__global__ void __launch_bounds__(64) wprep_o_kernel(const float* __restrict__ wc,
                                                     const float* __restrict__ w_out,
                                                     v8h* __restrict__ afragO) {
  int lane = threadIdx.x;
  int mt = blockIdx.x / 24, kstep = blockIdx.x % 24;
  int m = mt * 16 + (lane & 15), k0 = kstep * 32 + (lane >> 4) * 8;
  float e[8];
  if (k0 < CIN) {
    const float* s = wc + (size_t)m * CIN + k0;
#pragma unroll
    for (int j = 0; j < 8; j++) e[j] = s[j];
  } else {
    const float* s = w_out + (size_t)m * D_ + (k0 - CIN);
#pragma unroll
    for (int j = 0; j < 8; j++) e[j] = -s[j];
  }
  v8h h, l;
#pragma unroll
  for (int j = 0; j < 8; j++) {
    _Float16 hh = (_Float16)e[j];
    h[j] = hh; l[j] = (_Float16)(e[j] - (float)hh);
  }
  v8h* dst = afragO + ((size_t)blockIdx.x * 64 + lane) * 2;
  dst[0] = h; dst[1] = l;
}

// ---------------------------------------------------------------------------
// proj_x: split-3 f16 MFMA, m-split x2 (proven round-6 kernel, unchanged)
// ---------------------------------------------------------------------------
__global__ void __launch_bounds__(256, 4) proj_x_kernel(const float* __restrict__ emb,
                                                        const v8h* __restrict__ afragX,
                                                        float* __restrict__ rb) {
  int tid = threadIdx.x, wave = tid >> 6, lane = tid & 63;
  int lr = lane & 15, lg = lane >> 4;
  int tb = blockIdx.x >> 1, nb = blockIdx.x & 1;
  int t0 = tb * 64 + wave * 16;
  int b  = t0 >> 12;
  const float* ebase = emb + (size_t)b * CIN * T_ + (t0 & (T_ - 1)) + lr;

  v4f acc[8];
#pragma unroll
  for (int nt = 0; nt < 8; nt++) acc[nt] = (v4f){0.f, 0.f, 0.f, 0.f};

  for (int ks = 0; ks < 16; ks++) {
    float e[8];
#pragma unroll
    for (int j = 0; j < 8; j++)
      e[j] = ebase[(size_t)(ks * 32 + lg * 8 + j) * T_];
    v8h Eh, El;
#pragma unroll
    for (int j = 0; j < 8; j++) {
      _Float16 hh = (_Float16)e[j];
      Eh[j] = hh; El[j] = (_Float16)(e[j] - (float)hh);
    }
    const v8h* ap = afragX + ((size_t)ks * 64 + lane) * 2;
#pragma unroll
    for (int nt = 0; nt < 8; nt++) {
      int mt = nb * 8 + nt;
      v8h Wh = ap[(size_t)mt * 2048];
      v8h Wl = ap[(size_t)mt * 2048 + 1];
      acc[nt] = __builtin_amdgcn_mfma_f32_16x16x32_f16(Eh, Wh, acc[nt], 0, 0, 0);
      acc[nt] = __builtin_amdgcn_mfma_f32_16x16x32_f16(El, Wh, acc[nt], 0, 0, 0);
      acc[nt] = __builtin_amdgcn_mfma_f32_16x16x32_f16(Eh, Wl, acc[nt], 0, 0, 0);
    }
  }
#pragma unroll
  for (int nt = 0; nt < 8; nt++)
#pragma unroll
    for (int r = 0; r < 4; r++)
      rb[(size_t)(t0 + lg * 4 + r) * D_ + (nb * 8 + nt) * 16 + lr] = acc[nt][r];
}

// ---------------------------------------------------------------------------
// proj_out (proven round-5 kernel, unchanged)
// ---------------------------------------------------------------------------
__global__ void __launch_bounds__(256, 4) proj_out_kernel(const float* __restrict__ emb,
                                                          const float* __restrict__ rb,
                                                          const v8h* __restrict__ afragO,
                                                          float* __restrict__ outb) {
  int tid = threadIdx.x, wave = tid >> 6, lane = tid & 63;
  int lr = lane & 15, lg = lane >> 4;
  int tb = blockIdx.x >> 1, mb = blockIdx.x & 1;
  int t0 = tb * 64 + wave * 16;
  int b  = t0 >> 12;
  const float* ebase = emb + (size_t)b * CIN * T_ + (t0 & (T_ - 1)) + lr;

  v4f acc[16];
#pragma unroll
  for (int mt = 0; mt < 16; mt++) acc[mt] = (v4f){0.f, 0.f, 0.f, 0.f};

  for (int ks = 0; ks < 24; ks++) {
    float e[8];
    if (ks < 16) {
#pragma unroll
      for (int j = 0; j < 8; j++)
        e[j] = ebase[(size_t)(ks * 32 + lg * 8 + j) * T_];
    } else {
      const float* rrow = rb + (size_t)(t0 + lr) * D_ + (ks - 16) * 32 + lg * 8;
      float4 f0 = *(const float4*)rrow, f1 = *(const float4*)(rrow + 4);
      e[0] = f0.x; e[1] = f0.y; e[2] = f0.z; e[3] = f0.w;
      e[4] = f1.x; e[5] = f1.y; e[6] = f1.z; e[7] = f1.w;
    }
    v8h Bh;
#pragma unroll
    for (int j = 0; j < 8; j++) Bh[j] = (_Float16)e[j];
#pragma unroll
    for (int mt = 0; mt < 16; mt++) {
      v8h Ah = afragO[(((size_t)(mb * 16 + mt) * 24 + ks) * 64 + lane) * 2];
      acc[mt] = __builtin_amdgcn_mfma_f32_16x16x32_f16(Ah, Bh, acc[mt], 0, 0, 0);
    }
  }
  float* op = outb + (size_t)b * CIN * T_ + (t0 & (T_ - 1)) + lr;
#pragma unroll
  for (int mt = 0; mt < 16; mt++)
#pragma unroll
    for (int r = 0; r < 4; r++)
      op[(size_t)((mb * 16 + mt) * 16 + lg * 4 + r) * T_] = acc[mt][r];
}

// ---------------------------------------------------------------------------
// merge helper (proven round-6 code, unchanged)
// ---------------------------------------------------------------------------
__device__ __forceinline__ void merge_save(unsigned b1[4], unsigned b2[4], unsigned b3[4],
                                           int half, int wave, int lg, int lr,
                                           int (*candL)[6]) {
#pragma unroll
  for (int rI = 0; rI < 4; rI++) {
    unsigned k1 = b1[rI], k2 = b2[rI], k3 = b3[rI];
    int n1 = (int)(k1 & 127u) * 16 + lr;
    int n2 = (int)(k2 & 127u) * 16 + lr;
    int n3 = (int)(k3 & 127u) * 16 + lr;
    int o0 = 0, o1 = 0, o2v = 0;
#pragma unroll
    for (int round = 0; round < 3; round++) {
      unsigned mk = k1; int mn = n1;
#pragma unroll
      for (int st = 1; st < 16; st <<= 1) {
        unsigned ok = (unsigned)__shfl_xor((int)mk, st);
        int      on = __shfl_xor(mn, st);
        bool t = (ok < mk) || (ok == mk && on < mn);
        mk = t ? ok : mk; mn = t ? on : mn;
      }
      if (round == 0) o0 = mn; else if (round == 1) o1 = mn; else o2v = mn;
      bool own = (k1 == mk) && (n1 == mn);
      k1 = own ? k2 : k1; n1 = own ? n2 : n1;
      k2 = own ? k3 : k2; n2 = own ? n3 : n2;
      k3 = own ? 0xFFFFFFFFu : k3; n3 = own ? 0x7fffffff : n3;
    }
    if (lr == 0) {
      int* cp = candL[wave * 16 + lg * 4 + rI] + half * 3;
      cp[0] = o0; cp[1] = o1; cp[2] = o2v;
    }
  }
}

// ---------------------------------------------------------------------------
// Mega RVQ: all 8 steps in one kernel.  Residual lives in registers the
// whole time: thread (lg,lr) holds r64[64] = dims c*32+lg*8+j of token
// wbase+lr (== A-fragment layout).  Per step: A-rebuild (VALU only) ->
// full-codebook MFMA scan (round-6 math) -> in-register select (4 lanes
// per token via shfl over lg) -> in-register residual update.
// rb read once (prologue), written once (epilogue).
// ---------------------------------------------------------------------------
__global__ void __launch_bounds__(512, 2) rvq_mega_kernel(const _Float16* __restrict__ ehs,
                                                          const float* __restrict__ nrm,
                                                          const float* __restrict__ inv_,
                                                          const float* __restrict__ usage,
                                                          const float* __restrict__ embed_sum,
                                                          float* __restrict__ rb,
                                                          float* __restrict__ codes_f) {
  __shared__ v8h ldsB[2][1024];   // 32 KB: 2 buf x 2 chunks x 4096 f16
  __shared__ int candL[128][6];

  int tid  = threadIdx.x;
  int wave = tid >> 6, lane = tid & 63;
  int lr = lane & 15, lg = lane >> 4;
  int wbase = blockIdx.x * 128 + wave * 16;
  int token = wbase + lr;

  // prologue: load residual (A-frag layout), once
  float r64[64];
  {
    const float* rrow = rb + (size_t)token * D_ + lg * 8;
#pragma unroll
    for (int c = 0; c < 8; c++) {
      float4 f0 = *(const float4*)(rrow + c * 32);
      float4 f1 = *(const float4*)(rrow + c * 32 + 4);
      r64[c * 8 + 0] = f0.x; r64[c * 8 + 1] = f0.y;
      r64[c * 8 + 2] = f0.z; r64[c * 8 + 3] = f0.w;
      r64[c * 8 + 4] = f1.x; r64[c * 8 + 5] = f1.y;
      r64[c * 8 + 6] = f1.z; r64[c * 8 + 7] = f1.w;
    }
  }

  for (int k = 0; k < K_; k++) {
    // A fragments from register residual (pure VALU)
    v8h A[8];
#pragma unroll
    for (int c = 0; c < 8; c++) {
      v8h a;
#pragma unroll
      for (int j = 0; j < 8; j++) a[j] = (_Float16)r64[c * 8 + j];
      A[c] = a;
    }

    const v8h* src = (const v8h*)(ehs + (size_t)k * 2 * (64 * 4096));
    ldsB[0][tid]       = src[tid];
    ldsB[0][512 + tid] = src[512 + tid];

    unsigned b1[4], b2[4], b3[4];
#pragma unroll
    for (int i = 0; i < 4; i++) { b1[i] = b2[i] = b3[i] = 0xFFFFFFFFu; }
    const float* nrm_k = nrm + (size_t)k * N_;
    __syncthreads();

    for (int p = 0; p < 64; p++) {
      int cur = p & 1;
      v8h nxt0, nxt1;
      bool more = (p + 1 < 64);
      if (more) {
        nxt0 = src[(size_t)(p + 1) * 1024 + tid];        // issue early (T14)
        nxt1 = src[(size_t)(p + 1) * 1024 + 512 + tid];
      }

      v4f accA = {0.f, 0.f, 0.f, 0.f}, accB = {0.f, 0.f, 0.f, 0.f};
#pragma unroll
      for (int c = 0; c < 8; c++) {
        v8h BfA = ldsB[cur][(c * 4 + lg) * 16 + lr];
        v8h BfB = ldsB[cur][512 + (c * 4 + lg) * 16 + lr];
        accA = __builtin_amdgcn_mfma_f32_16x16x32_f16(A[c], BfA, accA, 0, 0, 0);
        accB = __builtin_amdgcn_mfma_f32_16x16x32_f16(A[c], BfB, accB, 0, 0, 0);
      }
      unsigned cgA = 2 * p, cgB = 2 * p + 1;
      float nvA = nrm_k[cgA * 16 + lr];                  // biased +2048 -> s > 0
      float nvB = nrm_k[cgB * 16 + lr];
#pragma unroll
      for (int j = 0; j < 4; j++) {
        {
          float s = fmaf(-2.0f, accA[j], nvA);
          unsigned pk = (__float_as_uint(s) & 0xFFFFFF80u) | cgA;
          unsigned t = umx(b1[j], pk);
          unsigned u = umx(b2[j], pk);
          b1[j] = umn(b1[j], pk);
          b2[j] = umn(b2[j], t);
          b3[j] = umn(b3[j], u);
        }
        {
          float s = fmaf(-2.0f, accB[j], nvB);
          unsigned pk = (__float_as_uint(s) & 0xFFFFFF80u) | cgB;
          unsigned t = umx(b1[j], pk);
          unsigned u = umx(b2[j], pk);
          b1[j] = umn(b1[j], pk);
          b2[j] = umn(b2[j], t);
          b3[j] = umn(b3[j], u);
        }
      }
      if (more) {
        ldsB[cur ^ 1][tid]       = nxt0;                 // write-late, other buffer
        ldsB[cur ^ 1][512 + tid] = nxt1;
      }
      if (p == 31) {                                     // end of half 0
        merge_save(b1, b2, b3, 0, wave, lg, lr, candL);
#pragma unroll
        for (int i = 0; i < 4; i++) { b1[i] = b2[i] = b3[i] = 0xFFFFFFFFu; }
      }
      __syncthreads();
    }
    merge_save(b1, b2, b3, 1, wave, lg, lr, candL);
    __syncthreads();

    // -------- select: 4 lg-lanes per token (lr), 64 dims each --------
    const float* es_k  = embed_sum + (size_t)k * N_ * D_;
    const float* us_k  = usage + (size_t)k * N_;
    const float* inv_k = inv_  + (size_t)k * N_;

    int c6[6];
#pragma unroll
    for (int i = 0; i < 6; i++) c6[i] = candL[wave * 16 + lr][i];

    float dots[6];
#pragma unroll
    for (int i = 0; i < 6; i++) {
      const float* sr = es_k + (size_t)c6[i] * D_ + lg * 8;
      float a = 0.f;
#pragma unroll
      for (int c = 0; c < 8; c++) {
        float4 s0 = *(const float4*)(sr + c * 32);
        float4 s1 = *(const float4*)(sr + c * 32 + 4);
        a += r64[c * 8 + 0] * s0.x + r64[c * 8 + 1] * s0.y
           + r64[c * 8 + 2] * s0.z + r64[c * 8 + 3] * s0.w
           + r64[c * 8 + 4] * s1.x + r64[c * 8 + 5] * s1.y
           + r64[c * 8 + 6] * s1.z + r64[c * 8 + 7] * s1.w;
      }
      dots[i] = a;
    }
#pragma unroll
    for (int i = 0; i < 6; i++) {
      dots[i] += __shfl_xor(dots[i], 16);
      dots[i] += __shfl_xor(dots[i], 32);
    }

    float bs = FLT_MAX, bv2 = FLT_MAX; int bn = 0x7fffffff, bn2 = 0x7fffffff;
#pragma unroll
    for (int i = 0; i < 6; i++) {
      int n = c6[i];
      float s = nrm_k[n] - 2.0f * inv_k[n] * dots[i];
      bool better = (s < bs) || (s == bs && n < bn);
      bool second = (s < bv2) || (s == bv2 && n < bn2);
      if (better)      { bv2 = bs; bn2 = bn; bs = s; bn = n; }
      else if (second) { bv2 = s;  bn2 = n; }
    }
    int winner = bn;
    if (bv2 - bs < 0.5f && bn2 != bn) {
      double sc[2]; int nn[2] = { bn, bn2 };
#pragma unroll
      for (int cI = 0; cI < 2; cI++) {
        double u = fmax((double)us_k[nn[cI]], 1e-5);
        double uinv = 1.0 / u;
        const float* srow = es_k + (size_t)nn[cI] * D_ + lg * 8;
        double dotre = 0.0, ee = 0.0;
#pragma unroll
        for (int c = 0; c < 8; c++) {
          float4 s0 = *(const float4*)(srow + c * 32);
          float4 s1 = *(const float4*)(srow + c * 32 + 4);
          double e0 = (double)s0.x * uinv, e1 = (double)s0.y * uinv;
          double e2 = (double)s0.z * uinv, e3 = (double)s0.w * uinv;
          double e4 = (double)s1.x * uinv, e5 = (double)s1.y * uinv;
          double e6 = (double)s1.z * uinv, e7 = (double)s1.w * uinv;
          dotre += (double)r64[c * 8 + 0] * e0 + (double)r64[c * 8 + 1] * e1
                 + (double)r64[c * 8 + 2] * e2 + (double)r64[c * 8 + 3] * e3
                 + (double)r64[c * 8 + 4] * e4 + (double)r64[c * 8 + 5] * e5
                 + (double)r64[c * 8 + 6] * e6 + (double)r64[c * 8 + 7] * e7;
          ee += e0 * e0 + e1 * e1 + e2 * e2 + e3 * e3
              + e4 * e4 + e5 * e5 + e6 * e6 + e7 * e7;
        }
        dotre += __shfl_xor(dotre, 16); dotre += __shfl_xor(dotre, 32);
        ee    += __shfl_xor(ee, 16);    ee    += __shfl_xor(ee, 32);
        sc[cI] = ee - 2.0 * dotre;
      }
      if (sc[1] < sc[0] || (sc[1] == sc[0] && nn[1] < nn[0])) winner = nn[1];
    }

    // residual update in registers (exact f32 s/um math)
    float um = fmaxf(us_k[winner], EPSF);
    const float* sw = es_k + (size_t)winner * D_ + lg * 8;
#pragma unroll
    for (int c = 0; c < 8; c++) {
      float4 s0 = *(const float4*)(sw + c * 32);
      float4 s1 = *(const float4*)(sw + c * 32 + 4);
      r64[c * 8 + 0] -= s0.x / um; r64[c * 8 + 1] -= s0.y / um;
      r64[c * 8 + 2] -= s0.z / um; r64[c * 8 + 3] -= s0.w / um;
      r64[c * 8 + 4] -= s1.x / um; r64[c * 8 + 5] -= s1.y / um;
      r64[c * 8 + 6] -= s1.z / um; r64[c * 8 + 7] -= s1.w / um;
    }
    if (lg == 0) codes_f[(size_t)k * BT + token] = (float)winner;
    // no extra barrier needed: next step's candL write (p==31) is gated by
    // the pre-p-loop __syncthreads, which every wave reaches after select.
  }

  // epilogue: write final residual back for proj_out
  {
    float* wrow = rb + (size_t)token * D_ + lg * 8;
#pragma unroll
    for (int c = 0; c < 8; c++) {
      float4 f0 = make_float4(r64[c * 8 + 0], r64[c * 8 + 1],
                              r64[c * 8 + 2], r64[c * 8 + 3]);
      float4 f1 = make_float4(r64[c * 8 + 4], r64[c * 8 + 5],
                              r64[c * 8 + 6], r64[c * 8 + 7]);
      *(float4*)(wrow + c * 32)     = f0;
      *(float4*)(wrow + c * 32 + 4) = f1;
    }
  }
}

// ---------------------------------------------------------------------------
extern "C" void kernel_launch(void* const* d_in, const int* in_sizes, int n_in,
                              void* d_out, int out_size, void* d_ws, size_t ws_size,
                              hipStream_t stream) {
  const float* emb       = (const float*)d_in[0];
  const float* w_in      = (const float*)d_in[1];
  const float* w_out     = (const float*)d_in[2];
  const float* embed_sum = (const float*)d_in[3];
  const float* usage     = (const float*)d_in[4];

  float* outp    = (float*)d_out;
  float* codes_f = outp;
  float* proj_o  = outp + (size_t)K_ * BT;

  float* rb   = (float*)d_ws;                          // BT*D f32 (33.55 MB)
  float* inv  = rb + (size_t)BT * D_;                  // K*N
  float* nrm  = inv + (size_t)K_ * N_;                 // K*N
  int*   cand = (int*)(nrm + (size_t)K_ * N_);         // (unused gap, kept)
  _Float16* ehs = (_Float16*)(cand + (size_t)BT * 6);  // K*N*D f16 (8.39 MB)
  v8h* afragX = (v8h*)(ehs + (size_t)K_ * N_ * D_);    // 512 KB
  float* wc   = (float*)(afragX + 16 * 16 * 64 * 2);   // 1 MB
  v8h* afragO = (v8h*)(wc + 512 * 512);                // 1.5 MB

  hipLaunchKernelGGL(wprep_x_kernel, dim3(256), dim3(64), 0, stream, w_in, afragX);
  hipLaunchKernelGGL(wc_kernel, dim3(1024), dim3(256), 0, stream, w_out, w_in, wc);
  hipLaunchKernelGGL(wprep_o_kernel, dim3(768), dim3(64), 0, stream, wc, w_out, afragO);
  hipLaunchKernelGGL(prep_kernel, dim3(K_ * N_ / 4), dim3(256), 0, stream,
                     embed_sum, usage, inv, nrm, ehs);
  hipLaunchKernelGGL(proj_x_kernel, dim3(BT / 32), dim3(256), 0, stream,
                     emb, afragX, rb);
  hipLaunchKernelGGL(rvq_mega_kernel, dim3(BT / 128), dim3(512), 0, stream,
                     ehs, nrm, inv, usage, embed_sum, rb, codes_f);
  hipLaunchKernelGGL(proj_out_kernel, dim3(BT / 32), dim3(256), 0, stream,
                     emb, rb, afragO, proj_o);
}